// Round 8
// baseline (637.796 us; speedup 1.0000x reference)
//
#include <hip/hip_runtime.h>

// ChebConv x2: N=100000, E=1600000, K=3, IN=128, HID=64, OUT=40
// Round 8:
//  - props: L2-resident feature-split sweeps. Gather sources stored
//    column-chunked ([4][N][16] bf16 for F=64, [5][N][8] for F=40) so each
//    sweep's source slice (<=3.2MB) fits per-XCD L2; sweep = blockIdx/bpS
//    gives temporal phase separation. Per sweep: LR=CH/4 lanes/row uint2
//    gathers (64/LR rows / 512B per instr), shfl_xor butterfly reduce,
//    epilogue on group 0 with addv/dinv hoisted pre-loop.
//  - CSR build (zero global atomics), MFMA GEMMs: as round 7; csr_src back
//    to plain indices; GEMM epilogues emit chunked bf16 gather buffers.

#define NBLK_PART 1024
#define MAXBUK 1024

typedef __attribute__((ext_vector_type(8))) short bf16x8;
typedef __attribute__((ext_vector_type(4))) float f32x4;

__device__ inline unsigned short f2bf(float f) {
  unsigned u = __float_as_uint(f);
  return (unsigned short)((u + 0x7FFFu + ((u >> 16) & 1u)) >> 16);
}
__device__ inline unsigned pk2(float a, float b) {
  return (unsigned)f2bf(a) | ((unsigned)f2bf(b) << 16);
}
__device__ inline float bflo(unsigned u) { return __uint_as_float(u << 16); }
__device__ inline float bfhi(unsigned u) { return __uint_as_float(u & 0xffff0000u); }

// pass A: per-block LDS histograms of dst>>7 and src>>7 (no global atomics)
__global__ __launch_bounds__(256) void k_passA(const int* __restrict__ src,
                                               const int* __restrict__ dst, int E, int cpb,
                                               int* __restrict__ histGd,
                                               int* __restrict__ histGs, int nbuk) {
  __shared__ int histD[MAXBUK], histS[MAXBUK];
  const int t = threadIdx.x, b = blockIdx.x;
  for (int k = t; k < nbuk; k += 256) {
    histD[k] = 0;
    histS[k] = 0;
  }
  __syncthreads();
  const int e0 = b * cpb;
  const int e1 = min(E, e0 + cpb);
  for (int e = e0 + t; e < e1; e += 256) {
    atomicAdd(&histD[dst[e] >> 7], 1);
    atomicAdd(&histS[src[e] >> 7], 1);
  }
  __syncthreads();
  for (int k = t; k < nbuk; k += 256) {
    histGd[k * NBLK_PART + b] = histD[k];
    histGs[k * NBLK_PART + b] = histS[k];
  }
}

// per bucket: exclusive scan over the 1024 partition blocks; grid = 2*nbuk
__global__ __launch_bounds__(256) void k_scanA(int* __restrict__ histGd,
                                               int* __restrict__ histGs,
                                               int* __restrict__ buktotD,
                                               int* __restrict__ buktotS, int nbuk) {
  __shared__ int sh[256];
  const int bb = blockIdx.x, t = threadIdx.x;
  int* hist = (bb < nbuk) ? histGd : histGs;
  int* tot = (bb < nbuk) ? buktotD : buktotS;
  const int b = (bb < nbuk) ? bb : bb - nbuk;
  const int base = b * NBLK_PART;
  int v[4];
  int s = 0;
#pragma unroll
  for (int i = 0; i < 4; i++) {
    v[i] = hist[base + t * 4 + i];
    s += v[i];
  }
  int run = s;
  sh[t] = run;
  __syncthreads();
  for (int off = 1; off < 256; off <<= 1) {
    int x = (t >= off) ? sh[t - off] : 0;
    __syncthreads();
    run += x;
    sh[t] = run;
    __syncthreads();
  }
  if (t == 255) tot[b] = run;
  int p = run - s;
#pragma unroll
  for (int i = 0; i < 4; i++) {
    hist[base + t * 4 + i] = p;
    p += v[i];
  }
}

// exclusive scan in place of two arrays (grid=2), nb <= 1024
__global__ __launch_bounds__(256) void k_scanB(int* __restrict__ aD, int* __restrict__ aS,
                                               int nb) {
  __shared__ int sh[256];
  int* a = (blockIdx.x == 0) ? aD : aS;
  const int t = threadIdx.x;
  int v[4];
  int s = 0;
#pragma unroll
  for (int i = 0; i < 4; i++) {
    int idx = t * 4 + i;
    v[i] = (idx < nb) ? a[idx] : 0;
    s += v[i];
  }
  int run = s;
  sh[t] = run;
  __syncthreads();
  for (int off = 1; off < 256; off <<= 1) {
    int x = (t >= off) ? sh[t - off] : 0;
    __syncthreads();
    run += x;
    sh[t] = run;
    __syncthreads();
  }
  int p = run - s;
#pragma unroll
  for (int i = 0; i < 4; i++) {
    int idx = t * 4 + i;
    if (idx < nb) a[idx] = p;
    p += v[i];
  }
}

// pass B: scatter (src<<7)|(dst&127) into dst-bucket order AND (src&127)
// bytes into src-bucket order, LDS cursors only
__global__ __launch_bounds__(256) void k_passB(const int* __restrict__ src,
                                               const int* __restrict__ dst, int E, int cpb,
                                               const int* __restrict__ histGd,
                                               const int* __restrict__ histGs,
                                               const int* __restrict__ bukoffD,
                                               const int* __restrict__ bukoffS, int nbuk,
                                               unsigned int* __restrict__ packed,
                                               unsigned char* __restrict__ pksrc) {
  __shared__ int curD[MAXBUK], curS[MAXBUK];
  const int t = threadIdx.x, b = blockIdx.x;
  for (int k = t; k < nbuk; k += 256) {
    curD[k] = bukoffD[k] + histGd[k * NBLK_PART + b];
    curS[k] = bukoffS[k] + histGs[k * NBLK_PART + b];
  }
  __syncthreads();
  const int e0 = b * cpb;
  const int e1 = min(E, e0 + cpb);
  for (int e = e0 + t; e < e1; e += 256) {
    int s = src[e], d = dst[e];
    int slot = atomicAdd(&curD[d >> 7], 1);
    packed[slot] = ((unsigned)s << 7) | (unsigned)(d & 127);
    int slot2 = atomicAdd(&curS[s >> 7], 1);
    pksrc[slot2] = (unsigned char)(s & 127);
  }
}

// pass C: per-bucket (128 nodes) CSR finalize fully in LDS; plain src indices
__global__ __launch_bounds__(256) void k_passC(const unsigned int* __restrict__ packed,
                                               const int* __restrict__ bukoff, int nbuk,
                                               int E, int n, int* __restrict__ csr_src,
                                               int* __restrict__ row_ptr) {
  __shared__ int cnt[128], scn[128], cur[128];
  const int t = threadIdx.x, b = blockIdx.x;
  if (t < 128) cnt[t] = 0;
  __syncthreads();
  const int e0 = bukoff[b];
  const int e1 = (b + 1 < nbuk) ? bukoff[b + 1] : E;
  for (int e = e0 + t; e < e1; e += 256) atomicAdd(&cnt[packed[e] & 127], 1);
  __syncthreads();
  if (t < 128) scn[t] = cnt[t];
  __syncthreads();
  for (int off = 1; off < 128; off <<= 1) {
    int x = (t < 128 && t >= off) ? scn[t - off] : 0;
    __syncthreads();
    if (t < 128) scn[t] += x;
    __syncthreads();
  }
  if (t < 128) {
    int start = e0 + scn[t] - cnt[t];
    cur[t] = start;
    int node = (b << 7) + t;
    if (node < n) row_ptr[node] = start;
  }
  if (b == 0 && t == 0) row_ptr[n] = E;
  __syncthreads();
  for (int e = e0 + t; e < e1; e += 256) {
    unsigned v = packed[e];
    int slot = atomicAdd(&cur[v & 127], 1);
    csr_src[slot] = (int)(v >> 7);
  }
}

// pass C2: per src-bucket degree count from bytes -> dinv
__global__ __launch_bounds__(256) void k_passC2(const unsigned char* __restrict__ pksrc,
                                                const int* __restrict__ bukoff, int nbuk,
                                                int E, int n, float* __restrict__ dinv) {
  __shared__ int cnt[128];
  const int t = threadIdx.x, b = blockIdx.x;
  if (t < 128) cnt[t] = 0;
  __syncthreads();
  const int e0 = bukoff[b];
  const int e1 = (b + 1 < nbuk) ? bukoff[b + 1] : E;
  for (int e = e0 + t; e < e1; e += 256) atomicAdd(&cnt[pksrc[e]], 1);
  __syncthreads();
  if (t < 128) {
    int node = (b << 7) + t;
    if (node < n) {
      int d = cnt[t];
      dinv[node] = (d > 0) ? rsqrtf((float)d) : 0.f;
    }
  }
}

// pre-swizzle effective weights into MFMA B-fragment order, bf16
__global__ void k_wfrag(const float* __restrict__ W, unsigned short* __restrict__ Wfrag,
                        int INF, int OUTC, int NT) {
  int idx = blockIdx.x * 256 + threadIdx.x;
  int total = (INF / 32) * NT * 64;
  if (idx >= total) return;
  int lane = idx & 63;
  int nt = (idx >> 6) % NT;
  int ks = idx / (64 * NT);
  int col = nt * 16 + (lane & 15);
  int kb = ks * 32 + (lane >> 4) * 8;
  unsigned short o8[8];
#pragma unroll
  for (int j = 0; j < 8; j++) {
    int k = kb + j;
    float v = 0.f;
    if (col < 3 * OUTC) {
      int m = col / OUTC, o = col - m * OUTC;
      if (m == 0)      v = W[(0 * INF + k) * OUTC + o] - W[(2 * INF + k) * OUTC + o];
      else if (m == 1) v = W[(1 * INF + k) * OUTC + o];
      else             v = 2.f * W[(2 * INF + k) * OUTC + o];
    }
    o8[j] = f2bf(v);
  }
  uint4 r;
  r.x = (unsigned)o8[0] | ((unsigned)o8[1] << 16);
  r.y = (unsigned)o8[2] | ((unsigned)o8[3] << 16);
  r.z = (unsigned)o8[4] | ((unsigned)o8[5] << 16);
  r.w = (unsigned)o8[6] | ((unsigned)o8[7] << 16);
  *reinterpret_cast<uint4*>(Wfrag + (size_t)idx * 8) = r;
}

// MFMA GEMM with split epilogue:
//   cols [0,C1)  -> Of0 fp32 stride S0
//   cols [C1,C2) -> Of1 fp32 stride S1
//   cols [C2,C3) -> Ob2 bf16 CHUNKED [(c/CHW)][n][CHW], scaled by dinv[row]
template <int INF, int NT, bool XBF16, int XSTR, int C1, int C2, int C3, int S0, int S1,
          int CHW>
__global__ __launch_bounds__(256) void k_gemm_mfma(const void* __restrict__ Xv,
                                                   const unsigned short* __restrict__ Wfrag,
                                                   const float* __restrict__ dinv,
                                                   float* __restrict__ Of0,
                                                   float* __restrict__ Of1,
                                                   unsigned short* __restrict__ Ob2, int n) {
  constexpr int KSTEPS = INF / 32;
  constexpr int KP = INF + 8;
  __shared__ unsigned short XA[64 * KP];
  const int tid = threadIdx.x;
  const int lane = tid & 63;
  const int w = tid >> 6;
  const int n0 = blockIdx.x * 64;
  // stage X -> bf16 LDS
  {
    const int node = tid >> 2;
    const int k0 = (tid & 3) * (INF / 4);
    const bool ok = (n0 + node) < n;
    unsigned short* dp = &XA[node * KP + k0];
    if (XBF16) {
      const unsigned short* sp = (const unsigned short*)Xv + (size_t)(n0 + node) * XSTR + k0;
#pragma unroll
      for (int i = 0; i < INF / 32; i++) {
        uint4 u = make_uint4(0, 0, 0, 0);
        if (ok) u = *reinterpret_cast<const uint4*>(sp + 8 * i);
        *reinterpret_cast<uint4*>(dp + 8 * i) = u;
      }
    } else {
      const float* sp = (const float*)Xv + (size_t)(n0 + node) * XSTR + k0;
#pragma unroll
      for (int i = 0; i < INF / 32; i++) {
        float4 va = make_float4(0.f, 0.f, 0.f, 0.f), vb = va;
        if (ok) {
          va = *reinterpret_cast<const float4*>(sp + 8 * i);
          vb = *reinterpret_cast<const float4*>(sp + 8 * i + 4);
        }
        uint4 u;
        u.x = pk2(va.x, va.y);
        u.y = pk2(va.z, va.w);
        u.z = pk2(vb.x, vb.y);
        u.w = pk2(vb.z, vb.w);
        *reinterpret_cast<uint4*>(dp + 8 * i) = u;
      }
    }
  }
  __syncthreads();
  bf16x8 afrag[KSTEPS];
  {
    const unsigned short* arow = &XA[(16 * w + (lane & 15)) * KP + (lane >> 4) * 8];
#pragma unroll
    for (int ks = 0; ks < KSTEPS; ks++)
      afrag[ks] = *reinterpret_cast<const bf16x8*>(arow + ks * 32);
  }
  f32x4 acc[NT];
#pragma unroll
  for (int nt = 0; nt < NT; nt++) acc[nt] = (f32x4){0.f, 0.f, 0.f, 0.f};
  const unsigned short* wf = Wfrag + (size_t)lane * 8;
#pragma unroll
  for (int ks = 0; ks < KSTEPS; ks++) {
#pragma unroll
    for (int nt = 0; nt < NT; nt++) {
      bf16x8 b = *reinterpret_cast<const bf16x8*>(wf + (size_t)(ks * NT + nt) * 512);
      acc[nt] = __builtin_amdgcn_mfma_f32_16x16x32_bf16(afrag[ks], b, acc[nt], 0, 0, 0);
    }
  }
  const int rq = (lane >> 4) * 4;
#pragma unroll
  for (int r = 0; r < 4; r++) {
    int row = n0 + 16 * w + rq + r;
    if (row < n) {
      float dv = dinv[row];
#pragma unroll
      for (int nt = 0; nt < NT; nt++) {
        int col = nt * 16 + (lane & 15);
        float v = acc[nt][r];
        if (col < C1) {
          Of0[(size_t)row * S0 + col] = v;
        } else if (col < C2) {
          Of1[(size_t)row * S1 + (col - C1)] = v;
        } else if (col < C3) {
          int c = col - C2;
          Ob2[((size_t)(c / CHW) * n + row) * CHW + (c % CHW)] = f2bf(v * dv);
        }
      }
    }
  }
}

// sweep-chunked CSR propagation: sweep s gathers chunk s ([n][CH] bf16,
// <=3.2MB -> per-XCD L2 resident). LR=CH/4 lanes/row (uint2 each), 64/LR
// rows per instruction; shfl_xor butterfly across groups; epilogue grp 0.
//   G = sum_j g[src[j]]; v = addv - dinv[d]*G (+bias) (*dinv) (relu)
// OMODE: 0 = bf16 chunk [s][n][CH]; 1 = bf16 full row stride OS; 2 = fp32 OS
template <int CH, int AS, int OS, bool RELU, bool BIAS, bool OUTSCALE, int OMODE>
__global__ __launch_bounds__(256) void k_prop7(const unsigned short* __restrict__ g,
                                               const float* __restrict__ addv,
                                               const float* __restrict__ bias,
                                               const float* __restrict__ dinv,
                                               const int* __restrict__ csr_src,
                                               const int* __restrict__ row_ptr,
                                               void* __restrict__ outv, int n, int bpS) {
  constexpr int LR = CH / 4;    // lanes per row
  constexpr int EPT = 64 / LR;  // edges per iteration
  const int s = blockIdx.x / bpS;
  const int nb = blockIdx.x - s * bpS;
  const int node = nb * 4 + (threadIdx.x >> 6);
  if (node >= n) return;
  const int lane = threadIdx.x & 63;
  const int grp = lane / LR;
  const int sub = lane % LR;
  const int beg = row_ptr[node];
  const int end = row_ptr[node + 1];
  const bool epi = (grp == 0);
  // hoist epilogue loads (independent of gathers)
  float4 av = make_float4(0.f, 0.f, 0.f, 0.f);
  float dv = 0.f;
  if (epi) {
    av = *reinterpret_cast<const float4*>(addv + (size_t)node * AS + s * CH + sub * 4);
    dv = dinv[node];
  }
  const char* gb = (const char*)(g + (size_t)s * n * CH) + sub * 8;
  float a0 = 0.f, a1 = 0.f, a2 = 0.f, a3 = 0.f;
  int j = beg;
  for (; j + EPT <= end; j += EPT) {
    int s0 = csr_src[j + grp];
    uint2 d = *reinterpret_cast<const uint2*>(gb + (size_t)s0 * (CH * 2));
    a0 += bflo(d.x); a1 += bfhi(d.x); a2 += bflo(d.y); a3 += bfhi(d.y);
  }
  if (j < end) {
    int e = j + grp;
    int s0 = csr_src[min(e, end - 1)];
    uint2 d = *reinterpret_cast<const uint2*>(gb + (size_t)s0 * (CH * 2));
    if (e >= end) { d.x = 0u; d.y = 0u; }
    a0 += bflo(d.x); a1 += bfhi(d.x); a2 += bflo(d.y); a3 += bfhi(d.y);
  }
#pragma unroll
  for (int m = LR; m < 64; m <<= 1) {
    a0 += __shfl_xor(a0, m);
    a1 += __shfl_xor(a1, m);
    a2 += __shfl_xor(a2, m);
    a3 += __shfl_xor(a3, m);
  }
  if (epi) {
    float v0 = av.x - dv * a0;
    float v1 = av.y - dv * a1;
    float v2 = av.z - dv * a2;
    float v3 = av.w - dv * a3;
    if (BIAS) {
      float4 bv = *reinterpret_cast<const float4*>(bias + s * CH + sub * 4);
      v0 += bv.x; v1 += bv.y; v2 += bv.z; v3 += bv.w;
    }
    if (OUTSCALE) { v0 *= dv; v1 *= dv; v2 *= dv; v3 *= dv; }
    if (RELU) {
      v0 = fmaxf(v0, 0.f); v1 = fmaxf(v1, 0.f);
      v2 = fmaxf(v2, 0.f); v3 = fmaxf(v3, 0.f);
    }
    if (OMODE == 0) {
      uint2 o;
      o.x = pk2(v0, v1);
      o.y = pk2(v2, v3);
      *reinterpret_cast<uint2*>((unsigned short*)outv + ((size_t)s * n + node) * CH +
                                sub * 4) = o;
    } else if (OMODE == 1) {
      uint2 o;
      o.x = pk2(v0, v1);
      o.y = pk2(v2, v3);
      *reinterpret_cast<uint2*>((unsigned short*)outv + (size_t)node * OS + s * CH +
                                sub * 4) = o;
    } else {
      *reinterpret_cast<float4*>((float*)outv + (size_t)node * OS + s * CH + sub * 4) =
          make_float4(v0, v1, v2, v3);
    }
  }
}

extern "C" void kernel_launch(void* const* d_in, const int* in_sizes, int n_in,
                              void* d_out, int out_size, void* d_ws, size_t ws_size,
                              hipStream_t stream) {
  const float* x  = (const float*)d_in[0];
  const int*   ei = (const int*)d_in[1];
  const float* W1 = (const float*)d_in[2];
  const float* b1 = (const float*)d_in[3];
  const float* W2 = (const float*)d_in[4];
  const float* b2 = (const float*)d_in[5];
  float* out = (float*)d_out;

  const int N = in_sizes[0] / 128;
  const int E = in_sizes[1] / 2;
  const int* src = ei;
  const int* dst = ei + E;

  const int nbuk = (N + 127) >> 7;
  if (nbuk > MAXBUK) return;
  const int cpb = (E + NBLK_PART - 1) / NBLK_PART;

  char* p = (char*)d_ws;
  size_t used = 0;
  auto alloc = [&](size_t bytes) -> void* {
    void* r = p + used;
    used += (bytes + 255) & ~(size_t)255;
    return r;
  };
  float* dinv    = (float*)alloc((size_t)N * 4);
  int*   row_ptr = (int*)alloc((size_t)(N + 1) * 4);
  int*   csr_src = (int*)alloc((size_t)E * 4);
  int*   buktotD = (int*)alloc((size_t)MAXBUK * 4);
  int*   buktotS = (int*)alloc((size_t)MAXBUK * 4);
  unsigned short* Wfrag1 = (unsigned short*)alloc((size_t)4 * 12 * 64 * 8 * 2);
  unsigned short* Wfrag2 = (unsigned short*)alloc((size_t)2 * 8 * 64 * 8 * 2);
  char* region = (char*)alloc((size_t)N * (64 * 4 * 2 + 64 * 2 * 2));  // 76.8 MB
  unsigned short* hb = (unsigned short*)alloc((size_t)N * 64 * 2);     // 12.8 MB
  if (used > ws_size) return;

  // layer-1 layout in region
  float* Y0f           = (float*)region;                          // [N,64] f32
  float* Y1f           = (float*)(region + (size_t)N * 64 * 4);   // [N,64] f32
  unsigned short* Ys2b = (unsigned short*)(region + (size_t)N * 64 * 8);  // [4][N][16] bf16
  unsigned short* Zsb  = (unsigned short*)(region + (size_t)N * 64 * 8 + (size_t)N * 64 * 2);
  // layer-2 layout aliases region (layer-1 dead by then)
  float* U0f           = (float*)region;                          // [N,40] f32
  float* U1f           = (float*)(region + (size_t)N * 40 * 4);   // [N,40] f32
  unsigned short* Us2b = (unsigned short*)(region + (size_t)N * 80 * 4);  // [5][N][8] bf16
  unsigned short* Z2sb = (unsigned short*)(region + (size_t)N * 80 * 4 + (size_t)N * 80);
  // radix temporaries alias region (dead before gemm1)
  unsigned int* packed = (unsigned int*)region;                    // E*4
  unsigned char* pksrc = (unsigned char*)(region + (size_t)E * 4); // E*1
  int* histGd = (int*)(region + (size_t)E * 5 + 256);
  int* histGs = histGd + (size_t)MAXBUK * NBLK_PART;

  k_passA<<<NBLK_PART, 256, 0, stream>>>(src, dst, E, cpb, histGd, histGs, nbuk);
  k_scanA<<<2 * nbuk, 256, 0, stream>>>(histGd, histGs, buktotD, buktotS, nbuk);
  k_scanB<<<2, 256, 0, stream>>>(buktotD, buktotS, nbuk);
  k_passB<<<NBLK_PART, 256, 0, stream>>>(src, dst, E, cpb, histGd, histGs, buktotD, buktotS,
                                         nbuk, packed, pksrc);
  k_passC<<<nbuk, 256, 0, stream>>>(packed, buktotD, nbuk, E, N, csr_src, row_ptr);
  k_passC2<<<nbuk, 256, 0, stream>>>(pksrc, buktotS, nbuk, E, N, dinv);

  k_wfrag<<<(4 * 12 * 64 + 255) / 256, 256, 0, stream>>>(W1, Wfrag1, 128, 64, 12);
  k_wfrag<<<(2 * 8 * 64 + 255) / 256, 256, 0, stream>>>(W2, Wfrag2, 64, 40, 8);

  const int gb = (N + 63) / 64;
  const int bpS = (N + 3) / 4;  // node-blocks per sweep (4 waves/block)

  // layer 1: [Y0|Y1|Ys2b-chunked] = bf16(x) @ Weff1 (Ys2 cols dinv-scaled)
  k_gemm_mfma<128, 12, false, 128, 64, 128, 192, 64, 64, 16>
      <<<gb, 256, 0, stream>>>(x, Wfrag1, dinv, Y0f, Y1f, Ys2b, N);
  // Zs = dinv*(Y1 - dinv*G(Ys2))  -> chunked bf16 [4][N][16]
  k_prop7<16, 64, 0, false, false, true, 0><<<4 * bpS, 256, 0, stream>>>(
      Ys2b, Y1f, nullptr, dinv, csr_src, row_ptr, Zsb, N, bpS);
  // h = relu(Y0 - dinv*G(Zs) + b1) -> full-row bf16 [N,64] (GEMM2 input)
  k_prop7<16, 64, 64, true, true, false, 1><<<4 * bpS, 256, 0, stream>>>(
      Zsb, Y0f, b1, dinv, csr_src, row_ptr, hb, N, bpS);
  // layer 2: [U0|U1|Us2b-chunked] = h @ Weff2 (Us2 cols dinv-scaled)
  k_gemm_mfma<64, 8, true, 64, 40, 80, 120, 40, 40, 8>
      <<<gb, 256, 0, stream>>>(hb, Wfrag2, dinv, U0f, U1f, Us2b, N);
  // Z2s = dinv*(U1 - dinv*G(Us2)) -> chunked bf16 [5][N][8]
  k_prop7<8, 40, 0, false, false, true, 0><<<5 * bpS, 256, 0, stream>>>(
      Us2b, U1f, nullptr, dinv, csr_src, row_ptr, Z2sb, N, bpS);
  // out = U0 - dinv*G(Z2s) + b2  (fp32 [N,40])
  k_prop7<8, 40, 40, false, true, false, 2><<<5 * bpS, 256, 0, stream>>>(
      Z2sb, U0f, b2, dinv, csr_src, row_ptr, out, N, bpS);
}

// Round 9
// 313.050 us; speedup vs baseline: 2.0374x; 2.0374x over previous
//
#include <hip/hip_runtime.h>

// ChebConv x2: N=100000, E=1600000, K=3, IN=128, HID=64, OUT=40
// Round 9 = round 7 structure (proven 343us) + higher-MLP prop loop:
//  - props: 8 lane-groups x 8 lanes, uint4 (16B) per lane -> one instruction
//    gathers 8 full 128B rows; unroll x2 (16 edges, 2 gathers in flight);
//    shfl_xor butterfly (8/16/32); epilogue = 8 cols/lane, 16B stores.
//  - CSR build with zero global atomics; csr_src = pre-scaled 128B row
//    byte offsets; MFMA bf16 GEMMs with split fp32/bf16 epilogues.

#define NBLK_PART 1024
#define MAXBUK 1024

typedef __attribute__((ext_vector_type(8))) short bf16x8;
typedef __attribute__((ext_vector_type(4))) float f32x4;

__device__ inline unsigned short f2bf(float f) {
  unsigned u = __float_as_uint(f);
  return (unsigned short)((u + 0x7FFFu + ((u >> 16) & 1u)) >> 16);
}
__device__ inline unsigned pk2(float a, float b) {
  return (unsigned)f2bf(a) | ((unsigned)f2bf(b) << 16);
}
__device__ inline float bflo(unsigned u) { return __uint_as_float(u << 16); }
__device__ inline float bfhi(unsigned u) { return __uint_as_float(u & 0xffff0000u); }

// pass A: per-block LDS histograms of dst>>7 and src>>7 (no global atomics)
__global__ __launch_bounds__(256) void k_passA(const int* __restrict__ src,
                                               const int* __restrict__ dst, int E, int cpb,
                                               int* __restrict__ histGd,
                                               int* __restrict__ histGs, int nbuk) {
  __shared__ int histD[MAXBUK], histS[MAXBUK];
  const int t = threadIdx.x, b = blockIdx.x;
  for (int k = t; k < nbuk; k += 256) {
    histD[k] = 0;
    histS[k] = 0;
  }
  __syncthreads();
  const int e0 = b * cpb;
  const int e1 = min(E, e0 + cpb);
  for (int e = e0 + t; e < e1; e += 256) {
    atomicAdd(&histD[dst[e] >> 7], 1);
    atomicAdd(&histS[src[e] >> 7], 1);
  }
  __syncthreads();
  for (int k = t; k < nbuk; k += 256) {
    histGd[k * NBLK_PART + b] = histD[k];
    histGs[k * NBLK_PART + b] = histS[k];
  }
}

// per bucket: exclusive scan over the 1024 partition blocks; grid = 2*nbuk
__global__ __launch_bounds__(256) void k_scanA(int* __restrict__ histGd,
                                               int* __restrict__ histGs,
                                               int* __restrict__ buktotD,
                                               int* __restrict__ buktotS, int nbuk) {
  __shared__ int sh[256];
  const int bb = blockIdx.x, t = threadIdx.x;
  int* hist = (bb < nbuk) ? histGd : histGs;
  int* tot = (bb < nbuk) ? buktotD : buktotS;
  const int b = (bb < nbuk) ? bb : bb - nbuk;
  const int base = b * NBLK_PART;
  int v[4];
  int s = 0;
#pragma unroll
  for (int i = 0; i < 4; i++) {
    v[i] = hist[base + t * 4 + i];
    s += v[i];
  }
  int run = s;
  sh[t] = run;
  __syncthreads();
  for (int off = 1; off < 256; off <<= 1) {
    int x = (t >= off) ? sh[t - off] : 0;
    __syncthreads();
    run += x;
    sh[t] = run;
    __syncthreads();
  }
  if (t == 255) tot[b] = run;
  int p = run - s;
#pragma unroll
  for (int i = 0; i < 4; i++) {
    hist[base + t * 4 + i] = p;
    p += v[i];
  }
}

// exclusive scan in place of two arrays (grid=2), nb <= 1024
__global__ __launch_bounds__(256) void k_scanB(int* __restrict__ aD, int* __restrict__ aS,
                                               int nb) {
  __shared__ int sh[256];
  int* a = (blockIdx.x == 0) ? aD : aS;
  const int t = threadIdx.x;
  int v[4];
  int s = 0;
#pragma unroll
  for (int i = 0; i < 4; i++) {
    int idx = t * 4 + i;
    v[i] = (idx < nb) ? a[idx] : 0;
    s += v[i];
  }
  int run = s;
  sh[t] = run;
  __syncthreads();
  for (int off = 1; off < 256; off <<= 1) {
    int x = (t >= off) ? sh[t - off] : 0;
    __syncthreads();
    run += x;
    sh[t] = run;
    __syncthreads();
  }
  int p = run - s;
#pragma unroll
  for (int i = 0; i < 4; i++) {
    int idx = t * 4 + i;
    if (idx < nb) a[idx] = p;
    p += v[i];
  }
}

// pass B: scatter (src<<7)|(dst&127) into dst-bucket order AND (src&127)
// bytes into src-bucket order, LDS cursors only
__global__ __launch_bounds__(256) void k_passB(const int* __restrict__ src,
                                               const int* __restrict__ dst, int E, int cpb,
                                               const int* __restrict__ histGd,
                                               const int* __restrict__ histGs,
                                               const int* __restrict__ bukoffD,
                                               const int* __restrict__ bukoffS, int nbuk,
                                               unsigned int* __restrict__ packed,
                                               unsigned char* __restrict__ pksrc) {
  __shared__ int curD[MAXBUK], curS[MAXBUK];
  const int t = threadIdx.x, b = blockIdx.x;
  for (int k = t; k < nbuk; k += 256) {
    curD[k] = bukoffD[k] + histGd[k * NBLK_PART + b];
    curS[k] = bukoffS[k] + histGs[k * NBLK_PART + b];
  }
  __syncthreads();
  const int e0 = b * cpb;
  const int e1 = min(E, e0 + cpb);
  for (int e = e0 + t; e < e1; e += 256) {
    int s = src[e], d = dst[e];
    int slot = atomicAdd(&curD[d >> 7], 1);
    packed[slot] = ((unsigned)s << 7) | (unsigned)(d & 127);
    int slot2 = atomicAdd(&curS[s >> 7], 1);
    pksrc[slot2] = (unsigned char)(s & 127);
  }
}

// pass C: per-bucket (128 nodes) CSR finalize fully in LDS.
// csr_src stores PRE-SCALED row byte offsets (src*128) for the bf16 gathers.
__global__ __launch_bounds__(256) void k_passC(const unsigned int* __restrict__ packed,
                                               const int* __restrict__ bukoff, int nbuk,
                                               int E, int n, int* __restrict__ csr_src,
                                               int* __restrict__ row_ptr) {
  __shared__ int cnt[128], scn[128], cur[128];
  const int t = threadIdx.x, b = blockIdx.x;
  if (t < 128) cnt[t] = 0;
  __syncthreads();
  const int e0 = bukoff[b];
  const int e1 = (b + 1 < nbuk) ? bukoff[b + 1] : E;
  for (int e = e0 + t; e < e1; e += 256) atomicAdd(&cnt[packed[e] & 127], 1);
  __syncthreads();
  if (t < 128) scn[t] = cnt[t];
  __syncthreads();
  for (int off = 1; off < 128; off <<= 1) {
    int x = (t < 128 && t >= off) ? scn[t - off] : 0;
    __syncthreads();
    if (t < 128) scn[t] += x;
    __syncthreads();
  }
  if (t < 128) {
    int start = e0 + scn[t] - cnt[t];
    cur[t] = start;
    int node = (b << 7) + t;
    if (node < n) row_ptr[node] = start;
  }
  if (b == 0 && t == 0) row_ptr[n] = E;
  __syncthreads();
  for (int e = e0 + t; e < e1; e += 256) {
    unsigned v = packed[e];
    int slot = atomicAdd(&cur[v & 127], 1);
    csr_src[slot] = (int)(v & ~127u);  // src*128 = byte offset of bf16[64] row
  }
}

// pass C2: per src-bucket degree count from bytes -> dinv
__global__ __launch_bounds__(256) void k_passC2(const unsigned char* __restrict__ pksrc,
                                                const int* __restrict__ bukoff, int nbuk,
                                                int E, int n, float* __restrict__ dinv) {
  __shared__ int cnt[128];
  const int t = threadIdx.x, b = blockIdx.x;
  if (t < 128) cnt[t] = 0;
  __syncthreads();
  const int e0 = bukoff[b];
  const int e1 = (b + 1 < nbuk) ? bukoff[b + 1] : E;
  for (int e = e0 + t; e < e1; e += 256) atomicAdd(&cnt[pksrc[e]], 1);
  __syncthreads();
  if (t < 128) {
    int node = (b << 7) + t;
    if (node < n) {
      int d = cnt[t];
      dinv[node] = (d > 0) ? rsqrtf((float)d) : 0.f;
    }
  }
}

// pre-swizzle effective weights into MFMA B-fragment order, bf16
__global__ void k_wfrag(const float* __restrict__ W, unsigned short* __restrict__ Wfrag,
                        int INF, int OUTC, int NT) {
  int idx = blockIdx.x * 256 + threadIdx.x;
  int total = (INF / 32) * NT * 64;
  if (idx >= total) return;
  int lane = idx & 63;
  int nt = (idx >> 6) % NT;
  int ks = idx / (64 * NT);
  int col = nt * 16 + (lane & 15);
  int kb = ks * 32 + (lane >> 4) * 8;
  unsigned short o8[8];
#pragma unroll
  for (int j = 0; j < 8; j++) {
    int k = kb + j;
    float v = 0.f;
    if (col < 3 * OUTC) {
      int m = col / OUTC, o = col - m * OUTC;
      if (m == 0)      v = W[(0 * INF + k) * OUTC + o] - W[(2 * INF + k) * OUTC + o];
      else if (m == 1) v = W[(1 * INF + k) * OUTC + o];
      else             v = 2.f * W[(2 * INF + k) * OUTC + o];
    }
    o8[j] = f2bf(v);
  }
  uint4 r;
  r.x = (unsigned)o8[0] | ((unsigned)o8[1] << 16);
  r.y = (unsigned)o8[2] | ((unsigned)o8[3] << 16);
  r.z = (unsigned)o8[4] | ((unsigned)o8[5] << 16);
  r.w = (unsigned)o8[6] | ((unsigned)o8[7] << 16);
  *reinterpret_cast<uint4*>(Wfrag + (size_t)idx * 8) = r;
}

// MFMA GEMM with split epilogue:
//   cols [0,C1)  -> Of0 fp32 stride S0
//   cols [C1,C2) -> Of1 fp32 stride S1
//   cols [C2,C3) -> Ob2 bf16 stride S2, scaled by dinv[row]
template <int INF, int NT, bool XBF16, int XSTR, int C1, int C2, int C3, int S0, int S1,
          int S2>
__global__ __launch_bounds__(256) void k_gemm_mfma(const void* __restrict__ Xv,
                                                   const unsigned short* __restrict__ Wfrag,
                                                   const float* __restrict__ dinv,
                                                   float* __restrict__ Of0,
                                                   float* __restrict__ Of1,
                                                   unsigned short* __restrict__ Ob2, int n) {
  constexpr int KSTEPS = INF / 32;
  constexpr int KP = INF + 8;
  __shared__ unsigned short XA[64 * KP];
  const int tid = threadIdx.x;
  const int lane = tid & 63;
  const int w = tid >> 6;
  const int n0 = blockIdx.x * 64;
  // stage X -> bf16 LDS
  {
    const int node = tid >> 2;
    const int k0 = (tid & 3) * (INF / 4);
    const bool ok = (n0 + node) < n;
    unsigned short* dp = &XA[node * KP + k0];
    if (XBF16) {
      const unsigned short* sp = (const unsigned short*)Xv + (size_t)(n0 + node) * XSTR + k0;
#pragma unroll
      for (int i = 0; i < INF / 32; i++) {
        uint4 u = make_uint4(0, 0, 0, 0);
        if (ok) u = *reinterpret_cast<const uint4*>(sp + 8 * i);
        *reinterpret_cast<uint4*>(dp + 8 * i) = u;
      }
    } else {
      const float* sp = (const float*)Xv + (size_t)(n0 + node) * XSTR + k0;
#pragma unroll
      for (int i = 0; i < INF / 32; i++) {
        float4 va = make_float4(0.f, 0.f, 0.f, 0.f), vb = va;
        if (ok) {
          va = *reinterpret_cast<const float4*>(sp + 8 * i);
          vb = *reinterpret_cast<const float4*>(sp + 8 * i + 4);
        }
        uint4 u;
        u.x = pk2(va.x, va.y);
        u.y = pk2(va.z, va.w);
        u.z = pk2(vb.x, vb.y);
        u.w = pk2(vb.z, vb.w);
        *reinterpret_cast<uint4*>(dp + 8 * i) = u;
      }
    }
  }
  __syncthreads();
  bf16x8 afrag[KSTEPS];
  {
    const unsigned short* arow = &XA[(16 * w + (lane & 15)) * KP + (lane >> 4) * 8];
#pragma unroll
    for (int ks = 0; ks < KSTEPS; ks++)
      afrag[ks] = *reinterpret_cast<const bf16x8*>(arow + ks * 32);
  }
  f32x4 acc[NT];
#pragma unroll
  for (int nt = 0; nt < NT; nt++) acc[nt] = (f32x4){0.f, 0.f, 0.f, 0.f};
  const unsigned short* wf = Wfrag + (size_t)lane * 8;
#pragma unroll
  for (int ks = 0; ks < KSTEPS; ks++) {
#pragma unroll
    for (int nt = 0; nt < NT; nt++) {
      bf16x8 b = *reinterpret_cast<const bf16x8*>(wf + (size_t)(ks * NT + nt) * 512);
      acc[nt] = __builtin_amdgcn_mfma_f32_16x16x32_bf16(afrag[ks], b, acc[nt], 0, 0, 0);
    }
  }
  const int rq = (lane >> 4) * 4;
#pragma unroll
  for (int r = 0; r < 4; r++) {
    int row = n0 + 16 * w + rq + r;
    if (row < n) {
      float dv = dinv[row];
#pragma unroll
      for (int nt = 0; nt < NT; nt++) {
        int col = nt * 16 + (lane & 15);
        float v = acc[nt][r];
        if (col < C1) {
          Of0[(size_t)row * S0 + col] = v;
        } else if (col < C2) {
          Of1[(size_t)row * S1 + (col - C1)] = v;
        } else if (col < C3) {
          Ob2[(size_t)row * S2 + (col - C2)] = f2bf(v * dv);
        }
      }
    }
  }
}

// wave-per-node CSR propagation, high-MLP gather:
// 8 lane-groups x 8 lanes; group g gathers the full 128B row of edge j+g as
// uint4 (16B/lane); unroll x2 (16 edges, 2 gathers in flight); csr_src holds
// pre-scaled row byte offsets. shfl_xor(8/16/32) butterfly; epilogue grp 0.
//   G = sum_j g[src[j]]; v = addv - dinv[d]*G (+bias) (*dinv) (relu)
template <int F, int AS, int OS, bool RELU, bool BIAS, bool OUTSCALE, bool OBF16>
__global__ __launch_bounds__(256) void k_prop8(const unsigned short* __restrict__ g,
                                               const float* __restrict__ addv,
                                               const float* __restrict__ bias,
                                               const float* __restrict__ dinv,
                                               const int* __restrict__ csr_src,
                                               const int* __restrict__ row_ptr,
                                               void* __restrict__ outv, int n) {
  constexpr int SUBW = (F + 7) / 8;  // active 16B slots per row (8 or 5)
  const int lane = threadIdx.x & 63;
  const int node = (blockIdx.x * blockDim.x + threadIdx.x) >> 6;
  if (node >= n) return;
  const int grp = lane >> 3;
  const int sub = lane & 7;
  const int beg = row_ptr[node];
  const int end = row_ptr[node + 1];
  const bool act = (SUBW == 8) || (sub < SUBW);
  const bool epi = (grp == 0) && act;
  // hoist epilogue operands (overlap with gather latency)
  float4 av0 = make_float4(0.f, 0.f, 0.f, 0.f), av1 = av0;
  float dv = dinv[node];
  if (epi) {
    const float* ap = addv + (size_t)node * AS + sub * 8;
    av0 = *reinterpret_cast<const float4*>(ap);
    av1 = *reinterpret_cast<const float4*>(ap + 4);
  }
  float a0 = 0.f, a1 = 0.f, a2 = 0.f, a3 = 0.f, a4 = 0.f, a5 = 0.f, a6 = 0.f, a7 = 0.f;
  float c0 = 0.f, c1 = 0.f, c2 = 0.f, c3 = 0.f, c4 = 0.f, c5 = 0.f, c6 = 0.f, c7 = 0.f;
  if (act) {
    const char* gb = (const char*)g + sub * 16;
    int j = beg;
    for (; j + 16 <= end; j += 16) {
      int sA = csr_src[j + grp];
      int sB = csr_src[j + 8 + grp];
      uint4 dA = *reinterpret_cast<const uint4*>(gb + sA);
      uint4 dB = *reinterpret_cast<const uint4*>(gb + sB);
      a0 += bflo(dA.x); a1 += bfhi(dA.x); a2 += bflo(dA.y); a3 += bfhi(dA.y);
      a4 += bflo(dA.z); a5 += bfhi(dA.z); a6 += bflo(dA.w); a7 += bfhi(dA.w);
      c0 += bflo(dB.x); c1 += bfhi(dB.x); c2 += bflo(dB.y); c3 += bfhi(dB.y);
      c4 += bflo(dB.z); c5 += bfhi(dB.z); c6 += bflo(dB.w); c7 += bfhi(dB.w);
    }
    for (; j < end; j += 8) {
      int e = j + grp;
      int s0 = csr_src[min(e, end - 1)];
      uint4 d = *reinterpret_cast<const uint4*>(gb + s0);
      if (e >= end) { d.x = 0u; d.y = 0u; d.z = 0u; d.w = 0u; }
      a0 += bflo(d.x); a1 += bfhi(d.x); a2 += bflo(d.y); a3 += bfhi(d.y);
      a4 += bflo(d.z); a5 += bfhi(d.z); a6 += bflo(d.w); a7 += bfhi(d.w);
    }
  }
  float r0 = a0 + c0, r1 = a1 + c1, r2 = a2 + c2, r3 = a3 + c3;
  float r4 = a4 + c4, r5 = a5 + c5, r6 = a6 + c6, r7 = a7 + c7;
#pragma unroll
  for (int m = 8; m < 64; m <<= 1) {
    r0 += __shfl_xor(r0, m); r1 += __shfl_xor(r1, m);
    r2 += __shfl_xor(r2, m); r3 += __shfl_xor(r3, m);
    r4 += __shfl_xor(r4, m); r5 += __shfl_xor(r5, m);
    r6 += __shfl_xor(r6, m); r7 += __shfl_xor(r7, m);
  }
  if (epi) {
    float v0 = av0.x - dv * r0;
    float v1 = av0.y - dv * r1;
    float v2 = av0.z - dv * r2;
    float v3 = av0.w - dv * r3;
    float v4 = av1.x - dv * r4;
    float v5 = av1.y - dv * r5;
    float v6 = av1.z - dv * r6;
    float v7 = av1.w - dv * r7;
    if (BIAS) {
      const float* bp = bias + sub * 8;
      float4 bv0 = *reinterpret_cast<const float4*>(bp);
      float4 bv1 = *reinterpret_cast<const float4*>(bp + 4);
      v0 += bv0.x; v1 += bv0.y; v2 += bv0.z; v3 += bv0.w;
      v4 += bv1.x; v5 += bv1.y; v6 += bv1.z; v7 += bv1.w;
    }
    if (OUTSCALE) {
      v0 *= dv; v1 *= dv; v2 *= dv; v3 *= dv;
      v4 *= dv; v5 *= dv; v6 *= dv; v7 *= dv;
    }
    if (RELU) {
      v0 = fmaxf(v0, 0.f); v1 = fmaxf(v1, 0.f); v2 = fmaxf(v2, 0.f); v3 = fmaxf(v3, 0.f);
      v4 = fmaxf(v4, 0.f); v5 = fmaxf(v5, 0.f); v6 = fmaxf(v6, 0.f); v7 = fmaxf(v7, 0.f);
    }
    if (OBF16) {
      uint4 o;
      o.x = pk2(v0, v1);
      o.y = pk2(v2, v3);
      o.z = pk2(v4, v5);
      o.w = pk2(v6, v7);
      *reinterpret_cast<uint4*>((unsigned short*)outv + (size_t)node * OS + sub * 8) = o;
    } else {
      float* op = (float*)outv + (size_t)node * OS + sub * 8;
      *reinterpret_cast<float4*>(op) = make_float4(v0, v1, v2, v3);
      *reinterpret_cast<float4*>(op + 4) = make_float4(v4, v5, v6, v7);
    }
  }
}

extern "C" void kernel_launch(void* const* d_in, const int* in_sizes, int n_in,
                              void* d_out, int out_size, void* d_ws, size_t ws_size,
                              hipStream_t stream) {
  const float* x  = (const float*)d_in[0];
  const int*   ei = (const int*)d_in[1];
  const float* W1 = (const float*)d_in[2];
  const float* b1 = (const float*)d_in[3];
  const float* W2 = (const float*)d_in[4];
  const float* b2 = (const float*)d_in[5];
  float* out = (float*)d_out;

  const int N = in_sizes[0] / 128;
  const int E = in_sizes[1] / 2;
  const int* src = ei;
  const int* dst = ei + E;

  const int nbuk = (N + 127) >> 7;
  if (nbuk > MAXBUK) return;
  const int cpb = (E + NBLK_PART - 1) / NBLK_PART;

  char* p = (char*)d_ws;
  size_t used = 0;
  auto alloc = [&](size_t bytes) -> void* {
    void* r = p + used;
    used += (bytes + 255) & ~(size_t)255;
    return r;
  };
  float* dinv    = (float*)alloc((size_t)N * 4);
  int*   row_ptr = (int*)alloc((size_t)(N + 1) * 4);
  int*   csr_src = (int*)alloc((size_t)E * 4);
  int*   buktotD = (int*)alloc((size_t)MAXBUK * 4);
  int*   buktotS = (int*)alloc((size_t)MAXBUK * 4);
  unsigned short* Wfrag1 = (unsigned short*)alloc((size_t)4 * 12 * 64 * 8 * 2);
  unsigned short* Wfrag2 = (unsigned short*)alloc((size_t)2 * 8 * 64 * 8 * 2);
  char* region = (char*)alloc((size_t)N * (64 * 4 * 2 + 64 * 2 * 2));  // 76.8 MB
  unsigned short* hb = (unsigned short*)alloc((size_t)N * 64 * 2);     // 12.8 MB
  if (used > ws_size) return;

  // layer-1 layout in region
  float* Y0f           = (float*)region;                               // [N,64] f32
  float* Y1f           = (float*)(region + (size_t)N * 64 * 4);        // [N,64] f32
  unsigned short* Ys2b = (unsigned short*)(region + (size_t)N * 64 * 8);       // [N,64] bf16
  unsigned short* Zsb  = (unsigned short*)(region + (size_t)N * 64 * 8 + (size_t)N * 64 * 2);
  // layer-2 layout aliases region (layer-1 dead by then)
  float* U0f           = (float*)region;                               // [N,40] f32
  float* U1f           = (float*)(region + (size_t)N * 40 * 4);        // [N,40] f32
  unsigned short* Us2b = (unsigned short*)(region + (size_t)N * 80 * 4);       // [N,64] bf16
  unsigned short* Z2sb = (unsigned short*)(region + (size_t)N * 80 * 4 + (size_t)N * 64 * 2);
  // radix temporaries alias region (dead before gemm1)
  unsigned int* packed = (unsigned int*)region;                        // E*4
  unsigned char* pksrc = (unsigned char*)(region + (size_t)E * 4);     // E*1
  int* histGd = (int*)(region + (size_t)E * 5 + 256);
  int* histGs = histGd + (size_t)MAXBUK * NBLK_PART;

  k_passA<<<NBLK_PART, 256, 0, stream>>>(src, dst, E, cpb, histGd, histGs, nbuk);
  k_scanA<<<2 * nbuk, 256, 0, stream>>>(histGd, histGs, buktotD, buktotS, nbuk);
  k_scanB<<<2, 256, 0, stream>>>(buktotD, buktotS, nbuk);
  k_passB<<<NBLK_PART, 256, 0, stream>>>(src, dst, E, cpb, histGd, histGs, buktotD, buktotS,
                                         nbuk, packed, pksrc);
  k_passC<<<nbuk, 256, 0, stream>>>(packed, buktotD, nbuk, E, N, csr_src, row_ptr);
  k_passC2<<<nbuk, 256, 0, stream>>>(pksrc, buktotS, nbuk, E, N, dinv);

  k_wfrag<<<(4 * 12 * 64 + 255) / 256, 256, 0, stream>>>(W1, Wfrag1, 128, 64, 12);
  k_wfrag<<<(2 * 8 * 64 + 255) / 256, 256, 0, stream>>>(W2, Wfrag2, 64, 40, 8);

  const int pb = ((size_t)N * 64 + 255) / 256;
  const int gb = (N + 63) / 64;

  // layer 1: [Y0|Y1|Ys2b] = bf16(x) @ Weff1 (Ys2 cols dinv-scaled, bf16)
  k_gemm_mfma<128, 12, false, 128, 64, 128, 192, 64, 64, 64>
      <<<gb, 256, 0, stream>>>(x, Wfrag1, dinv, Y0f, Y1f, Ys2b, N);
  // Zs = dinv*(Y1 - dinv*G(Ys2))  -> bf16
  k_prop8<64, 64, 64, false, false, true, true><<<pb, 256, 0, stream>>>(
      Ys2b, Y1f, nullptr, dinv, csr_src, row_ptr, Zsb, N);
  // h = relu(Y0 - dinv*G(Zs) + b1) -> bf16
  k_prop8<64, 64, 64, true, true, false, true><<<pb, 256, 0, stream>>>(
      Zsb, Y0f, b1, dinv, csr_src, row_ptr, hb, N);
  // layer 2: [U0|U1|Us2b] = h @ Weff2 (Us2 cols dinv-scaled, bf16)
  k_gemm_mfma<64, 8, true, 64, 40, 80, 120, 40, 40, 64>
      <<<gb, 256, 0, stream>>>(hb, Wfrag2, dinv, U0f, U1f, Us2b, N);
  // Z2s = dinv*(U1 - dinv*G(Us2)) -> bf16
  k_prop8<40, 40, 64, false, false, true, true><<<pb, 256, 0, stream>>>(
      Us2b, U1f, nullptr, dinv, csr_src, row_ptr, Z2sb, N);
  // out = U0 - dinv*G(Z2s) + b2  (fp32)
  k_prop8<40, 40, 40, false, true, false, false><<<pb, 256, 0, stream>>>(
      Z2sb, U0f, b2, dinv, csr_src, row_ptr, out, N);
}

// Round 11
// 293.687 us; speedup vs baseline: 2.1717x; 1.0659x over previous
//
#include <hip/hip_runtime.h>

// ChebConv x2: N=100000, E=1600000, K=3, IN=128, HID=64, OUT=40
// Round 11 = round 9 + 2-nodes-per-wave props ONLY (dot2 removed — it was
// the round-10 correctness bug suspect; arithmetic identical to round 9):
//  - half-wave per node, 4 groups x 8 lanes, uint4 full-row gathers,
//    unroll x2, butterfly shfl_xor(8/16), per-node fixed costs halved.
//  - CSR build with zero global atomics; csr_src = pre-scaled 128B row
//    byte offsets; MFMA bf16 GEMMs with split fp32/bf16 epilogues.

#define NBLK_PART 1024
#define MAXBUK 1024

typedef __attribute__((ext_vector_type(8))) short bf16x8;
typedef __attribute__((ext_vector_type(4))) float f32x4;

__device__ inline unsigned short f2bf(float f) {
  unsigned u = __float_as_uint(f);
  return (unsigned short)((u + 0x7FFFu + ((u >> 16) & 1u)) >> 16);
}
__device__ inline unsigned pk2(float a, float b) {
  return (unsigned)f2bf(a) | ((unsigned)f2bf(b) << 16);
}
__device__ inline float bflo(unsigned u) { return __uint_as_float(u << 16); }
__device__ inline float bfhi(unsigned u) { return __uint_as_float(u & 0xffff0000u); }

// pass A: per-block LDS histograms of dst>>7 and src>>7 (no global atomics)
__global__ __launch_bounds__(256) void k_passA(const int* __restrict__ src,
                                               const int* __restrict__ dst, int E, int cpb,
                                               int* __restrict__ histGd,
                                               int* __restrict__ histGs, int nbuk) {
  __shared__ int histD[MAXBUK], histS[MAXBUK];
  const int t = threadIdx.x, b = blockIdx.x;
  for (int k = t; k < nbuk; k += 256) {
    histD[k] = 0;
    histS[k] = 0;
  }
  __syncthreads();
  const int e0 = b * cpb;
  const int e1 = min(E, e0 + cpb);
  for (int e = e0 + t; e < e1; e += 256) {
    atomicAdd(&histD[dst[e] >> 7], 1);
    atomicAdd(&histS[src[e] >> 7], 1);
  }
  __syncthreads();
  for (int k = t; k < nbuk; k += 256) {
    histGd[k * NBLK_PART + b] = histD[k];
    histGs[k * NBLK_PART + b] = histS[k];
  }
}

// per bucket: exclusive scan over the 1024 partition blocks; grid = 2*nbuk
__global__ __launch_bounds__(256) void k_scanA(int* __restrict__ histGd,
                                               int* __restrict__ histGs,
                                               int* __restrict__ buktotD,
                                               int* __restrict__ buktotS, int nbuk) {
  __shared__ int sh[256];
  const int bb = blockIdx.x, t = threadIdx.x;
  int* hist = (bb < nbuk) ? histGd : histGs;
  int* tot = (bb < nbuk) ? buktotD : buktotS;
  const int b = (bb < nbuk) ? bb : bb - nbuk;
  const int base = b * NBLK_PART;
  int v[4];
  int s = 0;
#pragma unroll
  for (int i = 0; i < 4; i++) {
    v[i] = hist[base + t * 4 + i];
    s += v[i];
  }
  int run = s;
  sh[t] = run;
  __syncthreads();
  for (int off = 1; off < 256; off <<= 1) {
    int x = (t >= off) ? sh[t - off] : 0;
    __syncthreads();
    run += x;
    sh[t] = run;
    __syncthreads();
  }
  if (t == 255) tot[b] = run;
  int p = run - s;
#pragma unroll
  for (int i = 0; i < 4; i++) {
    hist[base + t * 4 + i] = p;
    p += v[i];
  }
}

// exclusive scan in place of two arrays (grid=2), nb <= 1024
__global__ __launch_bounds__(256) void k_scanB(int* __restrict__ aD, int* __restrict__ aS,
                                               int nb) {
  __shared__ int sh[256];
  int* a = (blockIdx.x == 0) ? aD : aS;
  const int t = threadIdx.x;
  int v[4];
  int s = 0;
#pragma unroll
  for (int i = 0; i < 4; i++) {
    int idx = t * 4 + i;
    v[i] = (idx < nb) ? a[idx] : 0;
    s += v[i];
  }
  int run = s;
  sh[t] = run;
  __syncthreads();
  for (int off = 1; off < 256; off <<= 1) {
    int x = (t >= off) ? sh[t - off] : 0;
    __syncthreads();
    run += x;
    sh[t] = run;
    __syncthreads();
  }
  int p = run - s;
#pragma unroll
  for (int i = 0; i < 4; i++) {
    int idx = t * 4 + i;
    if (idx < nb) a[idx] = p;
    p += v[i];
  }
}

// pass B: scatter (src<<7)|(dst&127) into dst-bucket order AND (src&127)
// bytes into src-bucket order, LDS cursors only
__global__ __launch_bounds__(256) void k_passB(const int* __restrict__ src,
                                               const int* __restrict__ dst, int E, int cpb,
                                               const int* __restrict__ histGd,
                                               const int* __restrict__ histGs,
                                               const int* __restrict__ bukoffD,
                                               const int* __restrict__ bukoffS, int nbuk,
                                               unsigned int* __restrict__ packed,
                                               unsigned char* __restrict__ pksrc) {
  __shared__ int curD[MAXBUK], curS[MAXBUK];
  const int t = threadIdx.x, b = blockIdx.x;
  for (int k = t; k < nbuk; k += 256) {
    curD[k] = bukoffD[k] + histGd[k * NBLK_PART + b];
    curS[k] = bukoffS[k] + histGs[k * NBLK_PART + b];
  }
  __syncthreads();
  const int e0 = b * cpb;
  const int e1 = min(E, e0 + cpb);
  for (int e = e0 + t; e < e1; e += 256) {
    int s = src[e], d = dst[e];
    int slot = atomicAdd(&curD[d >> 7], 1);
    packed[slot] = ((unsigned)s << 7) | (unsigned)(d & 127);
    int slot2 = atomicAdd(&curS[s >> 7], 1);
    pksrc[slot2] = (unsigned char)(s & 127);
  }
}

// pass C: per-bucket (128 nodes) CSR finalize fully in LDS.
// csr_src stores PRE-SCALED row byte offsets (src*128) for the bf16 gathers.
__global__ __launch_bounds__(256) void k_passC(const unsigned int* __restrict__ packed,
                                               const int* __restrict__ bukoff, int nbuk,
                                               int E, int n, int* __restrict__ csr_src,
                                               int* __restrict__ row_ptr) {
  __shared__ int cnt[128], scn[128], cur[128];
  const int t = threadIdx.x, b = blockIdx.x;
  if (t < 128) cnt[t] = 0;
  __syncthreads();
  const int e0 = bukoff[b];
  const int e1 = (b + 1 < nbuk) ? bukoff[b + 1] : E;
  for (int e = e0 + t; e < e1; e += 256) atomicAdd(&cnt[packed[e] & 127], 1);
  __syncthreads();
  if (t < 128) scn[t] = cnt[t];
  __syncthreads();
  for (int off = 1; off < 128; off <<= 1) {
    int x = (t < 128 && t >= off) ? scn[t - off] : 0;
    __syncthreads();
    if (t < 128) scn[t] += x;
    __syncthreads();
  }
  if (t < 128) {
    int start = e0 + scn[t] - cnt[t];
    cur[t] = start;
    int node = (b << 7) + t;
    if (node < n) row_ptr[node] = start;
  }
  if (b == 0 && t == 0) row_ptr[n] = E;
  __syncthreads();
  for (int e = e0 + t; e < e1; e += 256) {
    unsigned v = packed[e];
    int slot = atomicAdd(&cur[v & 127], 1);
    csr_src[slot] = (int)(v & ~127u);  // src*128 = byte offset of bf16[64] row
  }
}

// pass C2: per src-bucket degree count from bytes -> dinv
__global__ __launch_bounds__(256) void k_passC2(const unsigned char* __restrict__ pksrc,
                                                const int* __restrict__ bukoff, int nbuk,
                                                int E, int n, float* __restrict__ dinv) {
  __shared__ int cnt[128];
  const int t = threadIdx.x, b = blockIdx.x;
  if (t < 128) cnt[t] = 0;
  __syncthreads();
  const int e0 = bukoff[b];
  const int e1 = (b + 1 < nbuk) ? bukoff[b + 1] : E;
  for (int e = e0 + t; e < e1; e += 256) atomicAdd(&cnt[pksrc[e]], 1);
  __syncthreads();
  if (t < 128) {
    int node = (b << 7) + t;
    if (node < n) {
      int d = cnt[t];
      dinv[node] = (d > 0) ? rsqrtf((float)d) : 0.f;
    }
  }
}

// pre-swizzle effective weights into MFMA B-fragment order, bf16
__global__ void k_wfrag(const float* __restrict__ W, unsigned short* __restrict__ Wfrag,
                        int INF, int OUTC, int NT) {
  int idx = blockIdx.x * 256 + threadIdx.x;
  int total = (INF / 32) * NT * 64;
  if (idx >= total) return;
  int lane = idx & 63;
  int nt = (idx >> 6) % NT;
  int ks = idx / (64 * NT);
  int col = nt * 16 + (lane & 15);
  int kb = ks * 32 + (lane >> 4) * 8;
  unsigned short o8[8];
#pragma unroll
  for (int j = 0; j < 8; j++) {
    int k = kb + j;
    float v = 0.f;
    if (col < 3 * OUTC) {
      int m = col / OUTC, o = col - m * OUTC;
      if (m == 0)      v = W[(0 * INF + k) * OUTC + o] - W[(2 * INF + k) * OUTC + o];
      else if (m == 1) v = W[(1 * INF + k) * OUTC + o];
      else             v = 2.f * W[(2 * INF + k) * OUTC + o];
    }
    o8[j] = f2bf(v);
  }
  uint4 r;
  r.x = (unsigned)o8[0] | ((unsigned)o8[1] << 16);
  r.y = (unsigned)o8[2] | ((unsigned)o8[3] << 16);
  r.z = (unsigned)o8[4] | ((unsigned)o8[5] << 16);
  r.w = (unsigned)o8[6] | ((unsigned)o8[7] << 16);
  *reinterpret_cast<uint4*>(Wfrag + (size_t)idx * 8) = r;
}

// MFMA GEMM with split epilogue:
//   cols [0,C1)  -> Of0 fp32 stride S0
//   cols [C1,C2) -> Of1 fp32 stride S1
//   cols [C2,C3) -> Ob2 bf16 stride S2, scaled by dinv[row]
template <int INF, int NT, bool XBF16, int XSTR, int C1, int C2, int C3, int S0, int S1,
          int S2>
__global__ __launch_bounds__(256) void k_gemm_mfma(const void* __restrict__ Xv,
                                                   const unsigned short* __restrict__ Wfrag,
                                                   const float* __restrict__ dinv,
                                                   float* __restrict__ Of0,
                                                   float* __restrict__ Of1,
                                                   unsigned short* __restrict__ Ob2, int n) {
  constexpr int KSTEPS = INF / 32;
  constexpr int KP = INF + 8;
  __shared__ unsigned short XA[64 * KP];
  const int tid = threadIdx.x;
  const int lane = tid & 63;
  const int w = tid >> 6;
  const int n0 = blockIdx.x * 64;
  // stage X -> bf16 LDS
  {
    const int node = tid >> 2;
    const int k0 = (tid & 3) * (INF / 4);
    const bool ok = (n0 + node) < n;
    unsigned short* dp = &XA[node * KP + k0];
    if (XBF16) {
      const unsigned short* sp = (const unsigned short*)Xv + (size_t)(n0 + node) * XSTR + k0;
#pragma unroll
      for (int i = 0; i < INF / 32; i++) {
        uint4 u = make_uint4(0, 0, 0, 0);
        if (ok) u = *reinterpret_cast<const uint4*>(sp + 8 * i);
        *reinterpret_cast<uint4*>(dp + 8 * i) = u;
      }
    } else {
      const float* sp = (const float*)Xv + (size_t)(n0 + node) * XSTR + k0;
#pragma unroll
      for (int i = 0; i < INF / 32; i++) {
        float4 va = make_float4(0.f, 0.f, 0.f, 0.f), vb = va;
        if (ok) {
          va = *reinterpret_cast<const float4*>(sp + 8 * i);
          vb = *reinterpret_cast<const float4*>(sp + 8 * i + 4);
        }
        uint4 u;
        u.x = pk2(va.x, va.y);
        u.y = pk2(va.z, va.w);
        u.z = pk2(vb.x, vb.y);
        u.w = pk2(vb.z, vb.w);
        *reinterpret_cast<uint4*>(dp + 8 * i) = u;
      }
    }
  }
  __syncthreads();
  bf16x8 afrag[KSTEPS];
  {
    const unsigned short* arow = &XA[(16 * w + (lane & 15)) * KP + (lane >> 4) * 8];
#pragma unroll
    for (int ks = 0; ks < KSTEPS; ks++)
      afrag[ks] = *reinterpret_cast<const bf16x8*>(arow + ks * 32);
  }
  f32x4 acc[NT];
#pragma unroll
  for (int nt = 0; nt < NT; nt++) acc[nt] = (f32x4){0.f, 0.f, 0.f, 0.f};
  const unsigned short* wf = Wfrag + (size_t)lane * 8;
#pragma unroll
  for (int ks = 0; ks < KSTEPS; ks++) {
#pragma unroll
    for (int nt = 0; nt < NT; nt++) {
      bf16x8 b = *reinterpret_cast<const bf16x8*>(wf + (size_t)(ks * NT + nt) * 512);
      acc[nt] = __builtin_amdgcn_mfma_f32_16x16x32_bf16(afrag[ks], b, acc[nt], 0, 0, 0);
    }
  }
  const int rq = (lane >> 4) * 4;
#pragma unroll
  for (int r = 0; r < 4; r++) {
    int row = n0 + 16 * w + rq + r;
    if (row < n) {
      float dv = dinv[row];
#pragma unroll
      for (int nt = 0; nt < NT; nt++) {
        int col = nt * 16 + (lane & 15);
        float v = acc[nt][r];
        if (col < C1) {
          Of0[(size_t)row * S0 + col] = v;
        } else if (col < C2) {
          Of1[(size_t)row * S1 + (col - C1)] = v;
        } else if (col < C3) {
          Ob2[(size_t)row * S2 + (col - C2)] = f2bf(v * dv);
        }
      }
    }
  }
}

// 2-nodes-per-wave CSR propagation: half-wave per node, 4 groups x 8 lanes;
// group g gathers the full 128B row of edge j+g as uint4; unroll x2;
// bf16 extract+add accumulate (round-9 arithmetic); butterfly shfl_xor(8/16);
// epilogue on grp 0 of each half. csr_src = pre-scaled row byte offsets.
//   G = sum_j g[src[j]]; v = addv - dinv[d]*G (+bias) (*dinv) (relu)
template <int F, int AS, int OS, bool RELU, bool BIAS, bool OUTSCALE, bool OBF16>
__global__ __launch_bounds__(256) void k_prop9(const unsigned short* __restrict__ g,
                                               const float* __restrict__ addv,
                                               const float* __restrict__ bias,
                                               const float* __restrict__ dinv,
                                               const int* __restrict__ csr_src,
                                               const int* __restrict__ row_ptr,
                                               void* __restrict__ outv, int n) {
  constexpr int SUBW = (F + 7) / 8;  // active 16B slots per row (8 or 5)
  const int lane = threadIdx.x & 63;
  const int wid = (blockIdx.x * blockDim.x + threadIdx.x) >> 6;
  const int node = wid * 2 + (lane >> 5);
  const int grp = (lane >> 3) & 3;
  const int sub = lane & 7;
  const bool valid = node < n;
  const int nd = valid ? node : (n - 1);
  const int beg = row_ptr[nd];
  const int end = valid ? row_ptr[nd + 1] : beg;
  const float dv = dinv[nd];
  const bool act = valid && ((SUBW == 8) || (sub < SUBW));
  const bool epi = (grp == 0) && act;
  // hoist epilogue operands (overlap with gather latency)
  float4 av0 = make_float4(0.f, 0.f, 0.f, 0.f), av1 = av0;
  if (epi) {
    const float* ap = addv + (size_t)nd * AS + sub * 8;
    av0 = *reinterpret_cast<const float4*>(ap);
    av1 = *reinterpret_cast<const float4*>(ap + 4);
  }
  float a0 = 0.f, a1 = 0.f, a2 = 0.f, a3 = 0.f, a4 = 0.f, a5 = 0.f, a6 = 0.f, a7 = 0.f;
  float c0 = 0.f, c1 = 0.f, c2 = 0.f, c3 = 0.f, c4 = 0.f, c5 = 0.f, c6 = 0.f, c7 = 0.f;
  if (act) {
    const char* gb = (const char*)g + sub * 16;
    int j = beg;
    for (; j + 8 <= end; j += 8) {
      int sA = csr_src[j + grp];
      int sB = csr_src[j + 4 + grp];
      uint4 dA = *reinterpret_cast<const uint4*>(gb + sA);
      uint4 dB = *reinterpret_cast<const uint4*>(gb + sB);
      a0 += bflo(dA.x); a1 += bfhi(dA.x); a2 += bflo(dA.y); a3 += bfhi(dA.y);
      a4 += bflo(dA.z); a5 += bfhi(dA.z); a6 += bflo(dA.w); a7 += bfhi(dA.w);
      c0 += bflo(dB.x); c1 += bfhi(dB.x); c2 += bflo(dB.y); c3 += bfhi(dB.y);
      c4 += bflo(dB.z); c5 += bfhi(dB.z); c6 += bflo(dB.w); c7 += bfhi(dB.w);
    }
    for (; j < end; j += 4) {
      int e = j + grp;
      int s0 = csr_src[min(e, end - 1)];
      uint4 d = *reinterpret_cast<const uint4*>(gb + s0);
      if (e >= end) { d.x = 0u; d.y = 0u; d.z = 0u; d.w = 0u; }
      a0 += bflo(d.x); a1 += bfhi(d.x); a2 += bflo(d.y); a3 += bfhi(d.y);
      a4 += bflo(d.z); a5 += bfhi(d.z); a6 += bflo(d.w); a7 += bfhi(d.w);
    }
  }
  float r0 = a0 + c0, r1 = a1 + c1, r2 = a2 + c2, r3 = a3 + c3;
  float r4 = a4 + c4, r5 = a5 + c5, r6 = a6 + c6, r7 = a7 + c7;
#pragma unroll
  for (int m = 8; m < 32; m <<= 1) {
    r0 += __shfl_xor(r0, m); r1 += __shfl_xor(r1, m);
    r2 += __shfl_xor(r2, m); r3 += __shfl_xor(r3, m);
    r4 += __shfl_xor(r4, m); r5 += __shfl_xor(r5, m);
    r6 += __shfl_xor(r6, m); r7 += __shfl_xor(r7, m);
  }
  if (epi) {
    float v0 = av0.x - dv * r0;
    float v1 = av0.y - dv * r1;
    float v2 = av0.z - dv * r2;
    float v3 = av0.w - dv * r3;
    float v4 = av1.x - dv * r4;
    float v5 = av1.y - dv * r5;
    float v6 = av1.z - dv * r6;
    float v7 = av1.w - dv * r7;
    if (BIAS) {
      const float* bp = bias + sub * 8;
      float4 bv0 = *reinterpret_cast<const float4*>(bp);
      float4 bv1 = *reinterpret_cast<const float4*>(bp + 4);
      v0 += bv0.x; v1 += bv0.y; v2 += bv0.z; v3 += bv0.w;
      v4 += bv1.x; v5 += bv1.y; v6 += bv1.z; v7 += bv1.w;
    }
    if (OUTSCALE) {
      v0 *= dv; v1 *= dv; v2 *= dv; v3 *= dv;
      v4 *= dv; v5 *= dv; v6 *= dv; v7 *= dv;
    }
    if (RELU) {
      v0 = fmaxf(v0, 0.f); v1 = fmaxf(v1, 0.f); v2 = fmaxf(v2, 0.f); v3 = fmaxf(v3, 0.f);
      v4 = fmaxf(v4, 0.f); v5 = fmaxf(v5, 0.f); v6 = fmaxf(v6, 0.f); v7 = fmaxf(v7, 0.f);
    }
    if (OBF16) {
      uint4 o;
      o.x = pk2(v0, v1);
      o.y = pk2(v2, v3);
      o.z = pk2(v4, v5);
      o.w = pk2(v6, v7);
      *reinterpret_cast<uint4*>((unsigned short*)outv + (size_t)nd * OS + sub * 8) = o;
    } else {
      float* op = (float*)outv + (size_t)nd * OS + sub * 8;
      *reinterpret_cast<float4*>(op) = make_float4(v0, v1, v2, v3);
      *reinterpret_cast<float4*>(op + 4) = make_float4(v4, v5, v6, v7);
    }
  }
}

extern "C" void kernel_launch(void* const* d_in, const int* in_sizes, int n_in,
                              void* d_out, int out_size, void* d_ws, size_t ws_size,
                              hipStream_t stream) {
  const float* x  = (const float*)d_in[0];
  const int*   ei = (const int*)d_in[1];
  const float* W1 = (const float*)d_in[2];
  const float* b1 = (const float*)d_in[3];
  const float* W2 = (const float*)d_in[4];
  const float* b2 = (const float*)d_in[5];
  float* out = (float*)d_out;

  const int N = in_sizes[0] / 128;
  const int E = in_sizes[1] / 2;
  const int* src = ei;
  const int* dst = ei + E;

  const int nbuk = (N + 127) >> 7;
  if (nbuk > MAXBUK) return;
  const int cpb = (E + NBLK_PART - 1) / NBLK_PART;

  char* p = (char*)d_ws;
  size_t used = 0;
  auto alloc = [&](size_t bytes) -> void* {
    void* r = p + used;
    used += (bytes + 255) & ~(size_t)255;
    return r;
  };
  float* dinv    = (float*)alloc((size_t)N * 4);
  int*   row_ptr = (int*)alloc((size_t)(N + 1) * 4);
  int*   csr_src = (int*)alloc((size_t)E * 4);
  int*   buktotD = (int*)alloc((size_t)MAXBUK * 4);
  int*   buktotS = (int*)alloc((size_t)MAXBUK * 4);
  unsigned short* Wfrag1 = (unsigned short*)alloc((size_t)4 * 12 * 64 * 8 * 2);
  unsigned short* Wfrag2 = (unsigned short*)alloc((size_t)2 * 8 * 64 * 8 * 2);
  char* region = (char*)alloc((size_t)N * (64 * 4 * 2 + 64 * 2 * 2));  // 76.8 MB
  unsigned short* hb = (unsigned short*)alloc((size_t)N * 64 * 2);     // 12.8 MB
  if (used > ws_size) return;

  // layer-1 layout in region
  float* Y0f           = (float*)region;                               // [N,64] f32
  float* Y1f           = (float*)(region + (size_t)N * 64 * 4);        // [N,64] f32
  unsigned short* Ys2b = (unsigned short*)(region + (size_t)N * 64 * 8);       // [N,64] bf16
  unsigned short* Zsb  = (unsigned short*)(region + (size_t)N * 64 * 8 + (size_t)N * 64 * 2);
  // layer-2 layout aliases region (layer-1 dead by then)
  float* U0f           = (float*)region;                               // [N,40] f32
  float* U1f           = (float*)(region + (size_t)N * 40 * 4);        // [N,40] f32
  unsigned short* Us2b = (unsigned short*)(region + (size_t)N * 80 * 4);       // [N,64] bf16
  unsigned short* Z2sb = (unsigned short*)(region + (size_t)N * 80 * 4 + (size_t)N * 64 * 2);
  // radix temporaries alias region (dead before gemm1)
  unsigned int* packed = (unsigned int*)region;                        // E*4
  unsigned char* pksrc = (unsigned char*)(region + (size_t)E * 4);     // E*1
  int* histGd = (int*)(region + (size_t)E * 5 + 256);
  int* histGs = histGd + (size_t)MAXBUK * NBLK_PART;

  k_passA<<<NBLK_PART, 256, 0, stream>>>(src, dst, E, cpb, histGd, histGs, nbuk);
  k_scanA<<<2 * nbuk, 256, 0, stream>>>(histGd, histGs, buktotD, buktotS, nbuk);
  k_scanB<<<2, 256, 0, stream>>>(buktotD, buktotS, nbuk);
  k_passB<<<NBLK_PART, 256, 0, stream>>>(src, dst, E, cpb, histGd, histGs, buktotD, buktotS,
                                         nbuk, packed, pksrc);
  k_passC<<<nbuk, 256, 0, stream>>>(packed, buktotD, nbuk, E, N, csr_src, row_ptr);
  k_passC2<<<nbuk, 256, 0, stream>>>(pksrc, buktotS, nbuk, E, N, dinv);

  k_wfrag<<<(4 * 12 * 64 + 255) / 256, 256, 0, stream>>>(W1, Wfrag1, 128, 64, 12);
  k_wfrag<<<(2 * 8 * 64 + 255) / 256, 256, 0, stream>>>(W2, Wfrag2, 64, 40, 8);

  const int pb2 = ((size_t)N * 32 + 255) / 256;  // 2 nodes per wave
  const int gb = (N + 63) / 64;

  // layer 1: [Y0|Y1|Ys2b] = bf16(x) @ Weff1 (Ys2 cols dinv-scaled, bf16)
  k_gemm_mfma<128, 12, false, 128, 64, 128, 192, 64, 64, 64>
      <<<gb, 256, 0, stream>>>(x, Wfrag1, dinv, Y0f, Y1f, Ys2b, N);
  // Zs = dinv*(Y1 - dinv*G(Ys2))  -> bf16
  k_prop9<64, 64, 64, false, false, true, true><<<pb2, 256, 0, stream>>>(
      Ys2b, Y1f, nullptr, dinv, csr_src, row_ptr, Zsb, N);
  // h = relu(Y0 - dinv*G(Zs) + b1) -> bf16
  k_prop9<64, 64, 64, true, true, false, true><<<pb2, 256, 0, stream>>>(
      Zsb, Y0f, b1, dinv, csr_src, row_ptr, hb, N);
  // layer 2: [U0|U1|Us2b] = h @ Weff2 (Us2 cols dinv-scaled, bf16)
  k_gemm_mfma<64, 8, true, 64, 40, 80, 120, 40, 40, 64>
      <<<gb, 256, 0, stream>>>(hb, Wfrag2, dinv, U0f, U1f, Us2b, N);
  // Z2s = dinv*(U1 - dinv*G(Us2)) -> bf16
  k_prop9<40, 40, 64, false, false, true, true><<<pb2, 256, 0, stream>>>(
      Us2b, U1f, nullptr, dinv, csr_src, row_ptr, Z2sb, N);
  // out = U0 - dinv*G(Z2s) + b2  (fp32)
  k_prop9<40, 40, 40, false, true, false, false><<<pb2, 256, 0, stream>>>(
      Z2sb, U0f, b2, dinv, csr_src, row_ptr, out, N);
}

// Round 12
// 263.531 us; speedup vs baseline: 2.4202x; 1.1144x over previous
//
#include <hip/hip_runtime.h>

// ChebConv x2: N=100000, E=1600000, K=3, IN=128, HID=64, OUT=40
// Round 12 = round 11 +
//  (1) XCD-major cursor permutation in the radix scatter: histG block axis
//      permuted by permb(b)=(b&7)*128+(b>>3) so same-XCD blocks own
//      contiguous slot ranges per bucket -> scatter lines stay in one L2.
//  (2) residual buffers (Y0,Y1,U0,U1) in bf16: gemm writes + prop addv
//      streams halve.
//  Everything else identical to round 11 (proven 293.7us).

#define NBLK_PART 1024
#define MAXBUK 1024

typedef __attribute__((ext_vector_type(8))) short bf16x8;
typedef __attribute__((ext_vector_type(4))) float f32x4;

__device__ inline unsigned short f2bf(float f) {
  unsigned u = __float_as_uint(f);
  return (unsigned short)((u + 0x7FFFu + ((u >> 16) & 1u)) >> 16);
}
__device__ inline unsigned pk2(float a, float b) {
  return (unsigned)f2bf(a) | ((unsigned)f2bf(b) << 16);
}
__device__ inline float bflo(unsigned u) { return __uint_as_float(u << 16); }
__device__ inline float bfhi(unsigned u) { return __uint_as_float(u & 0xffff0000u); }

// XCD-major block permutation for cursor ranges (heuristic: XCD = b % 8)
__device__ inline int permb(int b) { return ((b & 7) << 7) | (b >> 3); }

// pass A: per-block LDS histograms of dst>>7 and src>>7 (no global atomics)
__global__ __launch_bounds__(256) void k_passA(const int* __restrict__ src,
                                               const int* __restrict__ dst, int E, int cpb,
                                               int* __restrict__ histGd,
                                               int* __restrict__ histGs, int nbuk) {
  __shared__ int histD[MAXBUK], histS[MAXBUK];
  const int t = threadIdx.x, b = blockIdx.x;
  for (int k = t; k < nbuk; k += 256) {
    histD[k] = 0;
    histS[k] = 0;
  }
  __syncthreads();
  const int e0 = b * cpb;
  const int e1 = min(E, e0 + cpb);
  for (int e = e0 + t; e < e1; e += 256) {
    atomicAdd(&histD[dst[e] >> 7], 1);
    atomicAdd(&histS[src[e] >> 7], 1);
  }
  __syncthreads();
  const int bp = permb(b);
  for (int k = t; k < nbuk; k += 256) {
    histGd[k * NBLK_PART + bp] = histD[k];
    histGs[k * NBLK_PART + bp] = histS[k];
  }
}

// per bucket: exclusive scan over the 1024 partition slots; grid = 2*nbuk
__global__ __launch_bounds__(256) void k_scanA(int* __restrict__ histGd,
                                               int* __restrict__ histGs,
                                               int* __restrict__ buktotD,
                                               int* __restrict__ buktotS, int nbuk) {
  __shared__ int sh[256];
  const int bb = blockIdx.x, t = threadIdx.x;
  int* hist = (bb < nbuk) ? histGd : histGs;
  int* tot = (bb < nbuk) ? buktotD : buktotS;
  const int b = (bb < nbuk) ? bb : bb - nbuk;
  const int base = b * NBLK_PART;
  int v[4];
  int s = 0;
#pragma unroll
  for (int i = 0; i < 4; i++) {
    v[i] = hist[base + t * 4 + i];
    s += v[i];
  }
  int run = s;
  sh[t] = run;
  __syncthreads();
  for (int off = 1; off < 256; off <<= 1) {
    int x = (t >= off) ? sh[t - off] : 0;
    __syncthreads();
    run += x;
    sh[t] = run;
    __syncthreads();
  }
  if (t == 255) tot[b] = run;
  int p = run - s;
#pragma unroll
  for (int i = 0; i < 4; i++) {
    hist[base + t * 4 + i] = p;
    p += v[i];
  }
}

// exclusive scan in place of two arrays (grid=2), nb <= 1024
__global__ __launch_bounds__(256) void k_scanB(int* __restrict__ aD, int* __restrict__ aS,
                                               int nb) {
  __shared__ int sh[256];
  int* a = (blockIdx.x == 0) ? aD : aS;
  const int t = threadIdx.x;
  int v[4];
  int s = 0;
#pragma unroll
  for (int i = 0; i < 4; i++) {
    int idx = t * 4 + i;
    v[i] = (idx < nb) ? a[idx] : 0;
    s += v[i];
  }
  int run = s;
  sh[t] = run;
  __syncthreads();
  for (int off = 1; off < 256; off <<= 1) {
    int x = (t >= off) ? sh[t - off] : 0;
    __syncthreads();
    run += x;
    sh[t] = run;
    __syncthreads();
  }
  int p = run - s;
#pragma unroll
  for (int i = 0; i < 4; i++) {
    int idx = t * 4 + i;
    if (idx < nb) a[idx] = p;
    p += v[i];
  }
}

// pass B: scatter (src<<7)|(dst&127) into dst-bucket order AND (src&127)
// bytes into src-bucket order, LDS cursors only; XCD-major cursor bases
__global__ __launch_bounds__(256) void k_passB(const int* __restrict__ src,
                                               const int* __restrict__ dst, int E, int cpb,
                                               const int* __restrict__ histGd,
                                               const int* __restrict__ histGs,
                                               const int* __restrict__ bukoffD,
                                               const int* __restrict__ bukoffS, int nbuk,
                                               unsigned int* __restrict__ packed,
                                               unsigned char* __restrict__ pksrc) {
  __shared__ int curD[MAXBUK], curS[MAXBUK];
  const int t = threadIdx.x, b = blockIdx.x;
  const int bp = permb(b);
  for (int k = t; k < nbuk; k += 256) {
    curD[k] = bukoffD[k] + histGd[k * NBLK_PART + bp];
    curS[k] = bukoffS[k] + histGs[k * NBLK_PART + bp];
  }
  __syncthreads();
  const int e0 = b * cpb;
  const int e1 = min(E, e0 + cpb);
  for (int e = e0 + t; e < e1; e += 256) {
    int s = src[e], d = dst[e];
    int slot = atomicAdd(&curD[d >> 7], 1);
    packed[slot] = ((unsigned)s << 7) | (unsigned)(d & 127);
    int slot2 = atomicAdd(&curS[s >> 7], 1);
    pksrc[slot2] = (unsigned char)(s & 127);
  }
}

// pass C: per-bucket (128 nodes) CSR finalize fully in LDS.
// csr_src stores PRE-SCALED row byte offsets (src*128) for the bf16 gathers.
__global__ __launch_bounds__(256) void k_passC(const unsigned int* __restrict__ packed,
                                               const int* __restrict__ bukoff, int nbuk,
                                               int E, int n, int* __restrict__ csr_src,
                                               int* __restrict__ row_ptr) {
  __shared__ int cnt[128], scn[128], cur[128];
  const int t = threadIdx.x, b = blockIdx.x;
  if (t < 128) cnt[t] = 0;
  __syncthreads();
  const int e0 = bukoff[b];
  const int e1 = (b + 1 < nbuk) ? bukoff[b + 1] : E;
  for (int e = e0 + t; e < e1; e += 256) atomicAdd(&cnt[packed[e] & 127], 1);
  __syncthreads();
  if (t < 128) scn[t] = cnt[t];
  __syncthreads();
  for (int off = 1; off < 128; off <<= 1) {
    int x = (t < 128 && t >= off) ? scn[t - off] : 0;
    __syncthreads();
    if (t < 128) scn[t] += x;
    __syncthreads();
  }
  if (t < 128) {
    int start = e0 + scn[t] - cnt[t];
    cur[t] = start;
    int node = (b << 7) + t;
    if (node < n) row_ptr[node] = start;
  }
  if (b == 0 && t == 0) row_ptr[n] = E;
  __syncthreads();
  for (int e = e0 + t; e < e1; e += 256) {
    unsigned v = packed[e];
    int slot = atomicAdd(&cur[v & 127], 1);
    csr_src[slot] = (int)(v & ~127u);  // src*128 = byte offset of bf16[64] row
  }
}

// pass C2: per src-bucket degree count from bytes -> dinv
__global__ __launch_bounds__(256) void k_passC2(const unsigned char* __restrict__ pksrc,
                                                const int* __restrict__ bukoff, int nbuk,
                                                int E, int n, float* __restrict__ dinv) {
  __shared__ int cnt[128];
  const int t = threadIdx.x, b = blockIdx.x;
  if (t < 128) cnt[t] = 0;
  __syncthreads();
  const int e0 = bukoff[b];
  const int e1 = (b + 1 < nbuk) ? bukoff[b + 1] : E;
  for (int e = e0 + t; e < e1; e += 256) atomicAdd(&cnt[pksrc[e]], 1);
  __syncthreads();
  if (t < 128) {
    int node = (b << 7) + t;
    if (node < n) {
      int d = cnt[t];
      dinv[node] = (d > 0) ? rsqrtf((float)d) : 0.f;
    }
  }
}

// pre-swizzle effective weights into MFMA B-fragment order, bf16
__global__ void k_wfrag(const float* __restrict__ W, unsigned short* __restrict__ Wfrag,
                        int INF, int OUTC, int NT) {
  int idx = blockIdx.x * 256 + threadIdx.x;
  int total = (INF / 32) * NT * 64;
  if (idx >= total) return;
  int lane = idx & 63;
  int nt = (idx >> 6) % NT;
  int ks = idx / (64 * NT);
  int col = nt * 16 + (lane & 15);
  int kb = ks * 32 + (lane >> 4) * 8;
  unsigned short o8[8];
#pragma unroll
  for (int j = 0; j < 8; j++) {
    int k = kb + j;
    float v = 0.f;
    if (col < 3 * OUTC) {
      int m = col / OUTC, o = col - m * OUTC;
      if (m == 0)      v = W[(0 * INF + k) * OUTC + o] - W[(2 * INF + k) * OUTC + o];
      else if (m == 1) v = W[(1 * INF + k) * OUTC + o];
      else             v = 2.f * W[(2 * INF + k) * OUTC + o];
    }
    o8[j] = f2bf(v);
  }
  uint4 r;
  r.x = (unsigned)o8[0] | ((unsigned)o8[1] << 16);
  r.y = (unsigned)o8[2] | ((unsigned)o8[3] << 16);
  r.z = (unsigned)o8[4] | ((unsigned)o8[5] << 16);
  r.w = (unsigned)o8[6] | ((unsigned)o8[7] << 16);
  *reinterpret_cast<uint4*>(Wfrag + (size_t)idx * 8) = r;
}

// MFMA GEMM, all-bf16 split epilogue:
//   cols [0,C1)  -> O0 bf16 stride S0
//   cols [C1,C2) -> O1 bf16 stride S1
//   cols [C2,C3) -> O2 bf16 stride S2, scaled by dinv[row]
template <int INF, int NT, bool XBF16, int XSTR, int C1, int C2, int C3, int S0, int S1,
          int S2>
__global__ __launch_bounds__(256) void k_gemm_mfma(const void* __restrict__ Xv,
                                                   const unsigned short* __restrict__ Wfrag,
                                                   const float* __restrict__ dinv,
                                                   unsigned short* __restrict__ O0,
                                                   unsigned short* __restrict__ O1,
                                                   unsigned short* __restrict__ O2, int n) {
  constexpr int KSTEPS = INF / 32;
  constexpr int KP = INF + 8;
  __shared__ unsigned short XA[64 * KP];
  const int tid = threadIdx.x;
  const int lane = tid & 63;
  const int w = tid >> 6;
  const int n0 = blockIdx.x * 64;
  // stage X -> bf16 LDS
  {
    const int node = tid >> 2;
    const int k0 = (tid & 3) * (INF / 4);
    const bool ok = (n0 + node) < n;
    unsigned short* dp = &XA[node * KP + k0];
    if (XBF16) {
      const unsigned short* sp = (const unsigned short*)Xv + (size_t)(n0 + node) * XSTR + k0;
#pragma unroll
      for (int i = 0; i < INF / 32; i++) {
        uint4 u = make_uint4(0, 0, 0, 0);
        if (ok) u = *reinterpret_cast<const uint4*>(sp + 8 * i);
        *reinterpret_cast<uint4*>(dp + 8 * i) = u;
      }
    } else {
      const float* sp = (const float*)Xv + (size_t)(n0 + node) * XSTR + k0;
#pragma unroll
      for (int i = 0; i < INF / 32; i++) {
        float4 va = make_float4(0.f, 0.f, 0.f, 0.f), vb = va;
        if (ok) {
          va = *reinterpret_cast<const float4*>(sp + 8 * i);
          vb = *reinterpret_cast<const float4*>(sp + 8 * i + 4);
        }
        uint4 u;
        u.x = pk2(va.x, va.y);
        u.y = pk2(va.z, va.w);
        u.z = pk2(vb.x, vb.y);
        u.w = pk2(vb.z, vb.w);
        *reinterpret_cast<uint4*>(dp + 8 * i) = u;
      }
    }
  }
  __syncthreads();
  bf16x8 afrag[KSTEPS];
  {
    const unsigned short* arow = &XA[(16 * w + (lane & 15)) * KP + (lane >> 4) * 8];
#pragma unroll
    for (int ks = 0; ks < KSTEPS; ks++)
      afrag[ks] = *reinterpret_cast<const bf16x8*>(arow + ks * 32);
  }
  f32x4 acc[NT];
#pragma unroll
  for (int nt = 0; nt < NT; nt++) acc[nt] = (f32x4){0.f, 0.f, 0.f, 0.f};
  const unsigned short* wf = Wfrag + (size_t)lane * 8;
#pragma unroll
  for (int ks = 0; ks < KSTEPS; ks++) {
#pragma unroll
    for (int nt = 0; nt < NT; nt++) {
      bf16x8 b = *reinterpret_cast<const bf16x8*>(wf + (size_t)(ks * NT + nt) * 512);
      acc[nt] = __builtin_amdgcn_mfma_f32_16x16x32_bf16(afrag[ks], b, acc[nt], 0, 0, 0);
    }
  }
  const int rq = (lane >> 4) * 4;
#pragma unroll
  for (int r = 0; r < 4; r++) {
    int row = n0 + 16 * w + rq + r;
    if (row < n) {
      float dv = dinv[row];
#pragma unroll
      for (int nt = 0; nt < NT; nt++) {
        int col = nt * 16 + (lane & 15);
        float v = acc[nt][r];
        if (col < C1) {
          O0[(size_t)row * S0 + col] = f2bf(v);
        } else if (col < C2) {
          O1[(size_t)row * S1 + (col - C1)] = f2bf(v);
        } else if (col < C3) {
          O2[(size_t)row * S2 + (col - C2)] = f2bf(v * dv);
        }
      }
    }
  }
}

// 2-nodes-per-wave CSR propagation: half-wave per node, 4 groups x 8 lanes;
// group g gathers the full 128B row of edge j+g as uint4; unroll x2;
// bf16 extract+add accumulate; butterfly shfl_xor(8/16); epilogue grp 0.
// addv is bf16 (stride AS elements). csr_src = pre-scaled row byte offsets.
//   G = sum_j g[src[j]]; v = addv - dinv[d]*G (+bias) (*dinv) (relu)
template <int F, int AS, int OS, bool RELU, bool BIAS, bool OUTSCALE, bool OBF16>
__global__ __launch_bounds__(256) void k_prop9(const unsigned short* __restrict__ g,
                                               const unsigned short* __restrict__ addv,
                                               const float* __restrict__ bias,
                                               const float* __restrict__ dinv,
                                               const int* __restrict__ csr_src,
                                               const int* __restrict__ row_ptr,
                                               void* __restrict__ outv, int n) {
  constexpr int SUBW = (F + 7) / 8;  // active 16B slots per row (8 or 5)
  const int lane = threadIdx.x & 63;
  const int wid = (blockIdx.x * blockDim.x + threadIdx.x) >> 6;
  const int node = wid * 2 + (lane >> 5);
  const int grp = (lane >> 3) & 3;
  const int sub = lane & 7;
  const bool valid = node < n;
  const int nd = valid ? node : (n - 1);
  const int beg = row_ptr[nd];
  const int end = valid ? row_ptr[nd + 1] : beg;
  const float dv = dinv[nd];
  const bool act = valid && ((SUBW == 8) || (sub < SUBW));
  const bool epi = (grp == 0) && act;
  // hoist epilogue operands (overlap with gather latency); addv is bf16
  float4 av0 = make_float4(0.f, 0.f, 0.f, 0.f), av1 = av0;
  if (epi) {
    const unsigned short* ap = addv + (size_t)nd * AS + sub * 8;
    uint4 a = *reinterpret_cast<const uint4*>(ap);
    av0 = make_float4(bflo(a.x), bfhi(a.x), bflo(a.y), bfhi(a.y));
    av1 = make_float4(bflo(a.z), bfhi(a.z), bflo(a.w), bfhi(a.w));
  }
  float a0 = 0.f, a1 = 0.f, a2 = 0.f, a3 = 0.f, a4 = 0.f, a5 = 0.f, a6 = 0.f, a7 = 0.f;
  float c0 = 0.f, c1 = 0.f, c2 = 0.f, c3 = 0.f, c4 = 0.f, c5 = 0.f, c6 = 0.f, c7 = 0.f;
  if (act) {
    const char* gb = (const char*)g + sub * 16;
    int j = beg;
    for (; j + 8 <= end; j += 8) {
      int sA = csr_src[j + grp];
      int sB = csr_src[j + 4 + grp];
      uint4 dA = *reinterpret_cast<const uint4*>(gb + sA);
      uint4 dB = *reinterpret_cast<const uint4*>(gb + sB);
      a0 += bflo(dA.x); a1 += bfhi(dA.x); a2 += bflo(dA.y); a3 += bfhi(dA.y);
      a4 += bflo(dA.z); a5 += bfhi(dA.z); a6 += bflo(dA.w); a7 += bfhi(dA.w);
      c0 += bflo(dB.x); c1 += bfhi(dB.x); c2 += bflo(dB.y); c3 += bfhi(dB.y);
      c4 += bflo(dB.z); c5 += bfhi(dB.z); c6 += bflo(dB.w); c7 += bfhi(dB.w);
    }
    for (; j < end; j += 4) {
      int e = j + grp;
      int s0 = csr_src[min(e, end - 1)];
      uint4 d = *reinterpret_cast<const uint4*>(gb + s0);
      if (e >= end) { d.x = 0u; d.y = 0u; d.z = 0u; d.w = 0u; }
      a0 += bflo(d.x); a1 += bfhi(d.x); a2 += bflo(d.y); a3 += bfhi(d.y);
      a4 += bflo(d.z); a5 += bfhi(d.z); a6 += bflo(d.w); a7 += bfhi(d.w);
    }
  }
  float r0 = a0 + c0, r1 = a1 + c1, r2 = a2 + c2, r3 = a3 + c3;
  float r4 = a4 + c4, r5 = a5 + c5, r6 = a6 + c6, r7 = a7 + c7;
#pragma unroll
  for (int m = 8; m < 32; m <<= 1) {
    r0 += __shfl_xor(r0, m); r1 += __shfl_xor(r1, m);
    r2 += __shfl_xor(r2, m); r3 += __shfl_xor(r3, m);
    r4 += __shfl_xor(r4, m); r5 += __shfl_xor(r5, m);
    r6 += __shfl_xor(r6, m); r7 += __shfl_xor(r7, m);
  }
  if (epi) {
    float v0 = av0.x - dv * r0;
    float v1 = av0.y - dv * r1;
    float v2 = av0.z - dv * r2;
    float v3 = av0.w - dv * r3;
    float v4 = av1.x - dv * r4;
    float v5 = av1.y - dv * r5;
    float v6 = av1.z - dv * r6;
    float v7 = av1.w - dv * r7;
    if (BIAS) {
      const float* bp = bias + sub * 8;
      float4 bv0 = *reinterpret_cast<const float4*>(bp);
      float4 bv1 = *reinterpret_cast<const float4*>(bp + 4);
      v0 += bv0.x; v1 += bv0.y; v2 += bv0.z; v3 += bv0.w;
      v4 += bv1.x; v5 += bv1.y; v6 += bv1.z; v7 += bv1.w;
    }
    if (OUTSCALE) {
      v0 *= dv; v1 *= dv; v2 *= dv; v3 *= dv;
      v4 *= dv; v5 *= dv; v6 *= dv; v7 *= dv;
    }
    if (RELU) {
      v0 = fmaxf(v0, 0.f); v1 = fmaxf(v1, 0.f); v2 = fmaxf(v2, 0.f); v3 = fmaxf(v3, 0.f);
      v4 = fmaxf(v4, 0.f); v5 = fmaxf(v5, 0.f); v6 = fmaxf(v6, 0.f); v7 = fmaxf(v7, 0.f);
    }
    if (OBF16) {
      uint4 o;
      o.x = pk2(v0, v1);
      o.y = pk2(v2, v3);
      o.z = pk2(v4, v5);
      o.w = pk2(v6, v7);
      *reinterpret_cast<uint4*>((unsigned short*)outv + (size_t)nd * OS + sub * 8) = o;
    } else {
      float* op = (float*)outv + (size_t)nd * OS + sub * 8;
      *reinterpret_cast<float4*>(op) = make_float4(v0, v1, v2, v3);
      *reinterpret_cast<float4*>(op + 4) = make_float4(v4, v5, v6, v7);
    }
  }
}

extern "C" void kernel_launch(void* const* d_in, const int* in_sizes, int n_in,
                              void* d_out, int out_size, void* d_ws, size_t ws_size,
                              hipStream_t stream) {
  const float* x  = (const float*)d_in[0];
  const int*   ei = (const int*)d_in[1];
  const float* W1 = (const float*)d_in[2];
  const float* b1 = (const float*)d_in[3];
  const float* W2 = (const float*)d_in[4];
  const float* b2 = (const float*)d_in[5];
  float* out = (float*)d_out;

  const int N = in_sizes[0] / 128;
  const int E = in_sizes[1] / 2;
  const int* src = ei;
  const int* dst = ei + E;

  const int nbuk = (N + 127) >> 7;
  if (nbuk > MAXBUK) return;
  const int cpb = (E + NBLK_PART - 1) / NBLK_PART;

  char* p = (char*)d_ws;
  size_t used = 0;
  auto alloc = [&](size_t bytes) -> void* {
    void* r = p + used;
    used += (bytes + 255) & ~(size_t)255;
    return r;
  };
  float* dinv    = (float*)alloc((size_t)N * 4);
  int*   row_ptr = (int*)alloc((size_t)(N + 1) * 4);
  int*   csr_src = (int*)alloc((size_t)E * 4);
  int*   buktotD = (int*)alloc((size_t)MAXBUK * 4);
  int*   buktotS = (int*)alloc((size_t)MAXBUK * 4);
  unsigned short* Wfrag1 = (unsigned short*)alloc((size_t)4 * 12 * 64 * 8 * 2);
  unsigned short* Wfrag2 = (unsigned short*)alloc((size_t)2 * 8 * 64 * 8 * 2);
  char* region = (char*)alloc((size_t)N * 512);                       // 51.2 MB
  unsigned short* hb = (unsigned short*)alloc((size_t)N * 64 * 2);    // 12.8 MB
  if (used > ws_size) return;

  // layer-1 layout in region (all bf16)
  unsigned short* Y0b  = (unsigned short*)region;                       // [N,64]
  unsigned short* Y1b  = (unsigned short*)(region + (size_t)N * 128);   // [N,64]
  unsigned short* Ys2b = (unsigned short*)(region + (size_t)N * 256);   // [N,64]
  unsigned short* Zsb  = (unsigned short*)(region + (size_t)N * 384);   // [N,64]
  // layer-2 layout aliases region (layer-1 dead by then)
  unsigned short* U0b  = (unsigned short*)region;                       // [N,40]
  unsigned short* U1b  = (unsigned short*)(region + (size_t)N * 80);    // [N,40]
  unsigned short* Us2b = (unsigned short*)(region + (size_t)N * 160);   // [N,64]
  unsigned short* Z2sb = (unsigned short*)(region + (size_t)N * 288);   // [N,64]
  // radix temporaries alias region (dead before gemm1)
  unsigned int* packed = (unsigned int*)region;                        // E*4
  unsigned char* pksrc = (unsigned char*)(region + (size_t)E * 4);     // E*1
  int* histGd = (int*)(region + (((size_t)E * 5 + 256 + 255) & ~(size_t)255));
  int* histGs = histGd + (size_t)MAXBUK * NBLK_PART;

  k_passA<<<NBLK_PART, 256, 0, stream>>>(src, dst, E, cpb, histGd, histGs, nbuk);
  k_scanA<<<2 * nbuk, 256, 0, stream>>>(histGd, histGs, buktotD, buktotS, nbuk);
  k_scanB<<<2, 256, 0, stream>>>(buktotD, buktotS, nbuk);
  k_passB<<<NBLK_PART, 256, 0, stream>>>(src, dst, E, cpb, histGd, histGs, buktotD, buktotS,
                                         nbuk, packed, pksrc);
  k_passC<<<nbuk, 256, 0, stream>>>(packed, buktotD, nbuk, E, N, csr_src, row_ptr);
  k_passC2<<<nbuk, 256, 0, stream>>>(pksrc, buktotS, nbuk, E, N, dinv);

  k_wfrag<<<(4 * 12 * 64 + 255) / 256, 256, 0, stream>>>(W1, Wfrag1, 128, 64, 12);
  k_wfrag<<<(2 * 8 * 64 + 255) / 256, 256, 0, stream>>>(W2, Wfrag2, 64, 40, 8);

  const int pb2 = ((size_t)N * 32 + 255) / 256;  // 2 nodes per wave
  const int gb = (N + 63) / 64;

  // layer 1: [Y0b|Y1b|Ys2b] = bf16(x) @ Weff1 (Ys2 cols dinv-scaled)
  k_gemm_mfma<128, 12, false, 128, 64, 128, 192, 64, 64, 64>
      <<<gb, 256, 0, stream>>>(x, Wfrag1, dinv, Y0b, Y1b, Ys2b, N);
  // Zs = dinv*(Y1 - dinv*G(Ys2))  -> bf16
  k_prop9<64, 64, 64, false, false, true, true><<<pb2, 256, 0, stream>>>(
      Ys2b, Y1b, nullptr, dinv, csr_src, row_ptr, Zsb, N);
  // h = relu(Y0 - dinv*G(Zs) + b1) -> bf16
  k_prop9<64, 64, 64, true, true, false, true><<<pb2, 256, 0, stream>>>(
      Zsb, Y0b, b1, dinv, csr_src, row_ptr, hb, N);
  // layer 2: [U0b|U1b|Us2b] = h @ Weff2 (Us2 cols dinv-scaled)
  k_gemm_mfma<64, 8, true, 64, 40, 80, 120, 40, 40, 64>
      <<<gb, 256, 0, stream>>>(hb, Wfrag2, dinv, U0b, U1b, Us2b, N);
  // Z2s = dinv*(U1 - dinv*G(Us2)) -> bf16
  k_prop9<40, 40, 64, false, false, true, true><<<pb2, 256, 0, stream>>>(
      Us2b, U1b, nullptr, dinv, csr_src, row_ptr, Z2sb, N);
  // out = U0 - dinv*G(Z2s) + b2  (fp32)
  k_prop9<40, 40, 40, false, true, false, false><<<pb2, 256, 0, stream>>>(
      Z2sb, U0b, b2, dinv, csr_src, row_ptr, out, N);
}

// Round 13
// 259.804 us; speedup vs baseline: 2.4549x; 1.0143x over previous
//
#include <hip/hip_runtime.h>

// ChebConv x2: N=100000, E=1600000, K=3, IN=128, HID=64, OUT=40
// Round 13 = round 12 + LDS-free MFMA GEMM:
//  - A-fragments loaded DIRECTLY from global (lane row = lane&15, k-slice =
//    (lane>>4)*8): bf16 path = 1 uint4/K-step, fp32 path = 2 float4 + pk2.
//    No LDS, no __syncthreads, no bank conflicts; waves independent.
//  - radix CSR build w/ XCD-major cursor permutation, bf16 residuals,
//    2-nodes-per-wave props: identical to round 12 (proven 263.5us).

#define NBLK_PART 1024
#define MAXBUK 1024

typedef __attribute__((ext_vector_type(8))) short bf16x8;
typedef __attribute__((ext_vector_type(4))) float f32x4;

__device__ inline unsigned short f2bf(float f) {
  unsigned u = __float_as_uint(f);
  return (unsigned short)((u + 0x7FFFu + ((u >> 16) & 1u)) >> 16);
}
__device__ inline unsigned pk2(float a, float b) {
  return (unsigned)f2bf(a) | ((unsigned)f2bf(b) << 16);
}
__device__ inline float bflo(unsigned u) { return __uint_as_float(u << 16); }
__device__ inline float bfhi(unsigned u) { return __uint_as_float(u & 0xffff0000u); }

// XCD-major block permutation for cursor ranges (heuristic: XCD = b % 8)
__device__ inline int permb(int b) { return ((b & 7) << 7) | (b >> 3); }

// pass A: per-block LDS histograms of dst>>7 and src>>7 (no global atomics)
__global__ __launch_bounds__(256) void k_passA(const int* __restrict__ src,
                                               const int* __restrict__ dst, int E, int cpb,
                                               int* __restrict__ histGd,
                                               int* __restrict__ histGs, int nbuk) {
  __shared__ int histD[MAXBUK], histS[MAXBUK];
  const int t = threadIdx.x, b = blockIdx.x;
  for (int k = t; k < nbuk; k += 256) {
    histD[k] = 0;
    histS[k] = 0;
  }
  __syncthreads();
  const int e0 = b * cpb;
  const int e1 = min(E, e0 + cpb);
  for (int e = e0 + t; e < e1; e += 256) {
    atomicAdd(&histD[dst[e] >> 7], 1);
    atomicAdd(&histS[src[e] >> 7], 1);
  }
  __syncthreads();
  const int bp = permb(b);
  for (int k = t; k < nbuk; k += 256) {
    histGd[k * NBLK_PART + bp] = histD[k];
    histGs[k * NBLK_PART + bp] = histS[k];
  }
}

// per bucket: exclusive scan over the 1024 partition slots; grid = 2*nbuk
__global__ __launch_bounds__(256) void k_scanA(int* __restrict__ histGd,
                                               int* __restrict__ histGs,
                                               int* __restrict__ buktotD,
                                               int* __restrict__ buktotS, int nbuk) {
  __shared__ int sh[256];
  const int bb = blockIdx.x, t = threadIdx.x;
  int* hist = (bb < nbuk) ? histGd : histGs;
  int* tot = (bb < nbuk) ? buktotD : buktotS;
  const int b = (bb < nbuk) ? bb : bb - nbuk;
  const int base = b * NBLK_PART;
  int v[4];
  int s = 0;
#pragma unroll
  for (int i = 0; i < 4; i++) {
    v[i] = hist[base + t * 4 + i];
    s += v[i];
  }
  int run = s;
  sh[t] = run;
  __syncthreads();
  for (int off = 1; off < 256; off <<= 1) {
    int x = (t >= off) ? sh[t - off] : 0;
    __syncthreads();
    run += x;
    sh[t] = run;
    __syncthreads();
  }
  if (t == 255) tot[b] = run;
  int p = run - s;
#pragma unroll
  for (int i = 0; i < 4; i++) {
    hist[base + t * 4 + i] = p;
    p += v[i];
  }
}

// exclusive scan in place of two arrays (grid=2), nb <= 1024
__global__ __launch_bounds__(256) void k_scanB(int* __restrict__ aD, int* __restrict__ aS,
                                               int nb) {
  __shared__ int sh[256];
  int* a = (blockIdx.x == 0) ? aD : aS;
  const int t = threadIdx.x;
  int v[4];
  int s = 0;
#pragma unroll
  for (int i = 0; i < 4; i++) {
    int idx = t * 4 + i;
    v[i] = (idx < nb) ? a[idx] : 0;
    s += v[i];
  }
  int run = s;
  sh[t] = run;
  __syncthreads();
  for (int off = 1; off < 256; off <<= 1) {
    int x = (t >= off) ? sh[t - off] : 0;
    __syncthreads();
    run += x;
    sh[t] = run;
    __syncthreads();
  }
  int p = run - s;
#pragma unroll
  for (int i = 0; i < 4; i++) {
    int idx = t * 4 + i;
    if (idx < nb) a[idx] = p;
    p += v[i];
  }
}

// pass B: scatter (src<<7)|(dst&127) into dst-bucket order AND (src&127)
// bytes into src-bucket order, LDS cursors only; XCD-major cursor bases
__global__ __launch_bounds__(256) void k_passB(const int* __restrict__ src,
                                               const int* __restrict__ dst, int E, int cpb,
                                               const int* __restrict__ histGd,
                                               const int* __restrict__ histGs,
                                               const int* __restrict__ bukoffD,
                                               const int* __restrict__ bukoffS, int nbuk,
                                               unsigned int* __restrict__ packed,
                                               unsigned char* __restrict__ pksrc) {
  __shared__ int curD[MAXBUK], curS[MAXBUK];
  const int t = threadIdx.x, b = blockIdx.x;
  const int bp = permb(b);
  for (int k = t; k < nbuk; k += 256) {
    curD[k] = bukoffD[k] + histGd[k * NBLK_PART + bp];
    curS[k] = bukoffS[k] + histGs[k * NBLK_PART + bp];
  }
  __syncthreads();
  const int e0 = b * cpb;
  const int e1 = min(E, e0 + cpb);
  for (int e = e0 + t; e < e1; e += 256) {
    int s = src[e], d = dst[e];
    int slot = atomicAdd(&curD[d >> 7], 1);
    packed[slot] = ((unsigned)s << 7) | (unsigned)(d & 127);
    int slot2 = atomicAdd(&curS[s >> 7], 1);
    pksrc[slot2] = (unsigned char)(s & 127);
  }
}

// pass C: per-bucket (128 nodes) CSR finalize fully in LDS.
// csr_src stores PRE-SCALED row byte offsets (src*128) for the bf16 gathers.
__global__ __launch_bounds__(256) void k_passC(const unsigned int* __restrict__ packed,
                                               const int* __restrict__ bukoff, int nbuk,
                                               int E, int n, int* __restrict__ csr_src,
                                               int* __restrict__ row_ptr) {
  __shared__ int cnt[128], scn[128], cur[128];
  const int t = threadIdx.x, b = blockIdx.x;
  if (t < 128) cnt[t] = 0;
  __syncthreads();
  const int e0 = bukoff[b];
  const int e1 = (b + 1 < nbuk) ? bukoff[b + 1] : E;
  for (int e = e0 + t; e < e1; e += 256) atomicAdd(&cnt[packed[e] & 127], 1);
  __syncthreads();
  if (t < 128) scn[t] = cnt[t];
  __syncthreads();
  for (int off = 1; off < 128; off <<= 1) {
    int x = (t < 128 && t >= off) ? scn[t - off] : 0;
    __syncthreads();
    if (t < 128) scn[t] += x;
    __syncthreads();
  }
  if (t < 128) {
    int start = e0 + scn[t] - cnt[t];
    cur[t] = start;
    int node = (b << 7) + t;
    if (node < n) row_ptr[node] = start;
  }
  if (b == 0 && t == 0) row_ptr[n] = E;
  __syncthreads();
  for (int e = e0 + t; e < e1; e += 256) {
    unsigned v = packed[e];
    int slot = atomicAdd(&cur[v & 127], 1);
    csr_src[slot] = (int)(v & ~127u);  // src*128 = byte offset of bf16[64] row
  }
}

// pass C2: per src-bucket degree count from bytes -> dinv
__global__ __launch_bounds__(256) void k_passC2(const unsigned char* __restrict__ pksrc,
                                                const int* __restrict__ bukoff, int nbuk,
                                                int E, int n, float* __restrict__ dinv) {
  __shared__ int cnt[128];
  const int t = threadIdx.x, b = blockIdx.x;
  if (t < 128) cnt[t] = 0;
  __syncthreads();
  const int e0 = bukoff[b];
  const int e1 = (b + 1 < nbuk) ? bukoff[b + 1] : E;
  for (int e = e0 + t; e < e1; e += 256) atomicAdd(&cnt[pksrc[e]], 1);
  __syncthreads();
  if (t < 128) {
    int node = (b << 7) + t;
    if (node < n) {
      int d = cnt[t];
      dinv[node] = (d > 0) ? rsqrtf((float)d) : 0.f;
    }
  }
}

// pre-swizzle effective weights into MFMA B-fragment order, bf16
__global__ void k_wfrag(const float* __restrict__ W, unsigned short* __restrict__ Wfrag,
                        int INF, int OUTC, int NT) {
  int idx = blockIdx.x * 256 + threadIdx.x;
  int total = (INF / 32) * NT * 64;
  if (idx >= total) return;
  int lane = idx & 63;
  int nt = (idx >> 6) % NT;
  int ks = idx / (64 * NT);
  int col = nt * 16 + (lane & 15);
  int kb = ks * 32 + (lane >> 4) * 8;
  unsigned short o8[8];
#pragma unroll
  for (int j = 0; j < 8; j++) {
    int k = kb + j;
    float v = 0.f;
    if (col < 3 * OUTC) {
      int m = col / OUTC, o = col - m * OUTC;
      if (m == 0)      v = W[(0 * INF + k) * OUTC + o] - W[(2 * INF + k) * OUTC + o];
      else if (m == 1) v = W[(1 * INF + k) * OUTC + o];
      else             v = 2.f * W[(2 * INF + k) * OUTC + o];
    }
    o8[j] = f2bf(v);
  }
  uint4 r;
  r.x = (unsigned)o8[0] | ((unsigned)o8[1] << 16);
  r.y = (unsigned)o8[2] | ((unsigned)o8[3] << 16);
  r.z = (unsigned)o8[4] | ((unsigned)o8[5] << 16);
  r.w = (unsigned)o8[6] | ((unsigned)o8[7] << 16);
  *reinterpret_cast<uint4*>(Wfrag + (size_t)idx * 8) = r;
}

// LDS-free MFMA GEMM, all-bf16 split epilogue:
//   A-fragments loaded directly from global: lane holds row (lane&15) of the
//   wave's 16-row tile, k-slice (lane>>4)*8, per K-step.
//   cols [0,C1) -> O0 bf16 S0; [C1,C2) -> O1 bf16 S1; [C2,C3) -> O2 bf16 S2
//   (O2 scaled by dinv[row]).
template <int INF, int NT, bool XBF16, int XSTR, int C1, int C2, int C3, int S0, int S1,
          int S2>
__global__ __launch_bounds__(256) void k_gemm_mfma(const void* __restrict__ Xv,
                                                   const unsigned short* __restrict__ Wfrag,
                                                   const float* __restrict__ dinv,
                                                   unsigned short* __restrict__ O0,
                                                   unsigned short* __restrict__ O1,
                                                   unsigned short* __restrict__ O2, int n) {
  constexpr int KSTEPS = INF / 32;
  const int lane = threadIdx.x & 63;
  const int w = threadIdx.x >> 6;
  const int base = blockIdx.x * 64 + 16 * w;  // this wave's 16-row tile
  const int arow = base + (lane & 15);
  const int k8 = (lane >> 4) * 8;
  const bool ok = arow < n;
  union U16 {
    uint4 u;
    bf16x8 b;
  };
  bf16x8 afrag[KSTEPS];
  if (XBF16) {
    const unsigned short* sp = (const unsigned short*)Xv + (size_t)(ok ? arow : 0) * XSTR + k8;
#pragma unroll
    for (int ks = 0; ks < KSTEPS; ks++) {
      U16 u;
      u.u = make_uint4(0, 0, 0, 0);
      if (ok) u.u = *reinterpret_cast<const uint4*>(sp + ks * 32);
      afrag[ks] = u.b;
    }
  } else {
    const float* sp = (const float*)Xv + (size_t)(ok ? arow : 0) * XSTR + k8;
#pragma unroll
    for (int ks = 0; ks < KSTEPS; ks++) {
      float4 va = make_float4(0.f, 0.f, 0.f, 0.f), vb = va;
      if (ok) {
        va = *reinterpret_cast<const float4*>(sp + ks * 32);
        vb = *reinterpret_cast<const float4*>(sp + ks * 32 + 4);
      }
      U16 u;
      u.u.x = pk2(va.x, va.y);
      u.u.y = pk2(va.z, va.w);
      u.u.z = pk2(vb.x, vb.y);
      u.u.w = pk2(vb.z, vb.w);
      afrag[ks] = u.b;
    }
  }
  f32x4 acc[NT];
#pragma unroll
  for (int nt = 0; nt < NT; nt++) acc[nt] = (f32x4){0.f, 0.f, 0.f, 0.f};
  const unsigned short* wf = Wfrag + (size_t)lane * 8;
#pragma unroll
  for (int ks = 0; ks < KSTEPS; ks++) {
#pragma unroll
    for (int nt = 0; nt < NT; nt++) {
      bf16x8 b = *reinterpret_cast<const bf16x8*>(wf + (size_t)(ks * NT + nt) * 512);
      acc[nt] = __builtin_amdgcn_mfma_f32_16x16x32_bf16(afrag[ks], b, acc[nt], 0, 0, 0);
    }
  }
  const int rq = (lane >> 4) * 4;
#pragma unroll
  for (int r = 0; r < 4; r++) {
    int row = base + rq + r;
    if (row < n) {
      float dv = dinv[row];
#pragma unroll
      for (int nt = 0; nt < NT; nt++) {
        int col = nt * 16 + (lane & 15);
        float v = acc[nt][r];
        if (col < C1) {
          O0[(size_t)row * S0 + col] = f2bf(v);
        } else if (col < C2) {
          O1[(size_t)row * S1 + (col - C1)] = f2bf(v);
        } else if (col < C3) {
          O2[(size_t)row * S2 + (col - C2)] = f2bf(v * dv);
        }
      }
    }
  }
}

// 2-nodes-per-wave CSR propagation: half-wave per node, 4 groups x 8 lanes;
// group g gathers the full 128B row of edge j+g as uint4; unroll x2;
// bf16 extract+add accumulate; butterfly shfl_xor(8/16); epilogue grp 0.
// addv is bf16 (stride AS elements). csr_src = pre-scaled row byte offsets.
//   G = sum_j g[src[j]]; v = addv - dinv[d]*G (+bias) (*dinv) (relu)
template <int F, int AS, int OS, bool RELU, bool BIAS, bool OUTSCALE, bool OBF16>
__global__ __launch_bounds__(256) void k_prop9(const unsigned short* __restrict__ g,
                                               const unsigned short* __restrict__ addv,
                                               const float* __restrict__ bias,
                                               const float* __restrict__ dinv,
                                               const int* __restrict__ csr_src,
                                               const int* __restrict__ row_ptr,
                                               void* __restrict__ outv, int n) {
  constexpr int SUBW = (F + 7) / 8;  // active 16B slots per row (8 or 5)
  const int lane = threadIdx.x & 63;
  const int wid = (blockIdx.x * blockDim.x + threadIdx.x) >> 6;
  const int node = wid * 2 + (lane >> 5);
  const int grp = (lane >> 3) & 3;
  const int sub = lane & 7;
  const bool valid = node < n;
  const int nd = valid ? node : (n - 1);
  const int beg = row_ptr[nd];
  const int end = valid ? row_ptr[nd + 1] : beg;
  const float dv = dinv[nd];
  const bool act = valid && ((SUBW == 8) || (sub < SUBW));
  const bool epi = (grp == 0) && act;
  // hoist epilogue operands (overlap with gather latency); addv is bf16
  float4 av0 = make_float4(0.f, 0.f, 0.f, 0.f), av1 = av0;
  if (epi) {
    const unsigned short* ap = addv + (size_t)nd * AS + sub * 8;
    uint4 a = *reinterpret_cast<const uint4*>(ap);
    av0 = make_float4(bflo(a.x), bfhi(a.x), bflo(a.y), bfhi(a.y));
    av1 = make_float4(bflo(a.z), bfhi(a.z), bflo(a.w), bfhi(a.w));
  }
  float a0 = 0.f, a1 = 0.f, a2 = 0.f, a3 = 0.f, a4 = 0.f, a5 = 0.f, a6 = 0.f, a7 = 0.f;
  float c0 = 0.f, c1 = 0.f, c2 = 0.f, c3 = 0.f, c4 = 0.f, c5 = 0.f, c6 = 0.f, c7 = 0.f;
  if (act) {
    const char* gb = (const char*)g + sub * 16;
    int j = beg;
    for (; j + 8 <= end; j += 8) {
      int sA = csr_src[j + grp];
      int sB = csr_src[j + 4 + grp];
      uint4 dA = *reinterpret_cast<const uint4*>(gb + sA);
      uint4 dB = *reinterpret_cast<const uint4*>(gb + sB);
      a0 += bflo(dA.x); a1 += bfhi(dA.x); a2 += bflo(dA.y); a3 += bfhi(dA.y);
      a4 += bflo(dA.z); a5 += bfhi(dA.z); a6 += bflo(dA.w); a7 += bfhi(dA.w);
      c0 += bflo(dB.x); c1 += bfhi(dB.x); c2 += bflo(dB.y); c3 += bfhi(dB.y);
      c4 += bflo(dB.z); c5 += bfhi(dB.z); c6 += bflo(dB.w); c7 += bfhi(dB.w);
    }
    for (; j < end; j += 4) {
      int e = j + grp;
      int s0 = csr_src[min(e, end - 1)];
      uint4 d = *reinterpret_cast<const uint4*>(gb + s0);
      if (e >= end) { d.x = 0u; d.y = 0u; d.z = 0u; d.w = 0u; }
      a0 += bflo(d.x); a1 += bfhi(d.x); a2 += bflo(d.y); a3 += bfhi(d.y);
      a4 += bflo(d.z); a5 += bfhi(d.z); a6 += bflo(d.w); a7 += bfhi(d.w);
    }
  }
  float r0 = a0 + c0, r1 = a1 + c1, r2 = a2 + c2, r3 = a3 + c3;
  float r4 = a4 + c4, r5 = a5 + c5, r6 = a6 + c6, r7 = a7 + c7;
#pragma unroll
  for (int m = 8; m < 32; m <<= 1) {
    r0 += __shfl_xor(r0, m); r1 += __shfl_xor(r1, m);
    r2 += __shfl_xor(r2, m); r3 += __shfl_xor(r3, m);
    r4 += __shfl_xor(r4, m); r5 += __shfl_xor(r5, m);
    r6 += __shfl_xor(r6, m); r7 += __shfl_xor(r7, m);
  }
  if (epi) {
    float v0 = av0.x - dv * r0;
    float v1 = av0.y - dv * r1;
    float v2 = av0.z - dv * r2;
    float v3 = av0.w - dv * r3;
    float v4 = av1.x - dv * r4;
    float v5 = av1.y - dv * r5;
    float v6 = av1.z - dv * r6;
    float v7 = av1.w - dv * r7;
    if (BIAS) {
      const float* bp = bias + sub * 8;
      float4 bv0 = *reinterpret_cast<const float4*>(bp);
      float4 bv1 = *reinterpret_cast<const float4*>(bp + 4);
      v0 += bv0.x; v1 += bv0.y; v2 += bv0.z; v3 += bv0.w;
      v4 += bv1.x; v5 += bv1.y; v6 += bv1.z; v7 += bv1.w;
    }
    if (OUTSCALE) {
      v0 *= dv; v1 *= dv; v2 *= dv; v3 *= dv;
      v4 *= dv; v5 *= dv; v6 *= dv; v7 *= dv;
    }
    if (RELU) {
      v0 = fmaxf(v0, 0.f); v1 = fmaxf(v1, 0.f); v2 = fmaxf(v2, 0.f); v3 = fmaxf(v3, 0.f);
      v4 = fmaxf(v4, 0.f); v5 = fmaxf(v5, 0.f); v6 = fmaxf(v6, 0.f); v7 = fmaxf(v7, 0.f);
    }
    if (OBF16) {
      uint4 o;
      o.x = pk2(v0, v1);
      o.y = pk2(v2, v3);
      o.z = pk2(v4, v5);
      o.w = pk2(v6, v7);
      *reinterpret_cast<uint4*>((unsigned short*)outv + (size_t)nd * OS + sub * 8) = o;
    } else {
      float* op = (float*)outv + (size_t)nd * OS + sub * 8;
      *reinterpret_cast<float4*>(op) = make_float4(v0, v1, v2, v3);
      *reinterpret_cast<float4*>(op + 4) = make_float4(v4, v5, v6, v7);
    }
  }
}

extern "C" void kernel_launch(void* const* d_in, const int* in_sizes, int n_in,
                              void* d_out, int out_size, void* d_ws, size_t ws_size,
                              hipStream_t stream) {
  const float* x  = (const float*)d_in[0];
  const int*   ei = (const int*)d_in[1];
  const float* W1 = (const float*)d_in[2];
  const float* b1 = (const float*)d_in[3];
  const float* W2 = (const float*)d_in[4];
  const float* b2 = (const float*)d_in[5];
  float* out = (float*)d_out;

  const int N = in_sizes[0] / 128;
  const int E = in_sizes[1] / 2;
  const int* src = ei;
  const int* dst = ei + E;

  const int nbuk = (N + 127) >> 7;
  if (nbuk > MAXBUK) return;
  const int cpb = (E + NBLK_PART - 1) / NBLK_PART;

  char* p = (char*)d_ws;
  size_t used = 0;
  auto alloc = [&](size_t bytes) -> void* {
    void* r = p + used;
    used += (bytes + 255) & ~(size_t)255;
    return r;
  };
  float* dinv    = (float*)alloc((size_t)N * 4);
  int*   row_ptr = (int*)alloc((size_t)(N + 1) * 4);
  int*   csr_src = (int*)alloc((size_t)E * 4);
  int*   buktotD = (int*)alloc((size_t)MAXBUK * 4);
  int*   buktotS = (int*)alloc((size_t)MAXBUK * 4);
  unsigned short* Wfrag1 = (unsigned short*)alloc((size_t)4 * 12 * 64 * 8 * 2);
  unsigned short* Wfrag2 = (unsigned short*)alloc((size_t)2 * 8 * 64 * 8 * 2);
  char* region = (char*)alloc((size_t)N * 512);                       // 51.2 MB
  unsigned short* hb = (unsigned short*)alloc((size_t)N * 64 * 2);    // 12.8 MB
  if (used > ws_size) return;

  // layer-1 layout in region (all bf16)
  unsigned short* Y0b  = (unsigned short*)region;                       // [N,64]
  unsigned short* Y1b  = (unsigned short*)(region + (size_t)N * 128);   // [N,64]
  unsigned short* Ys2b = (unsigned short*)(region + (size_t)N * 256);   // [N,64]
  unsigned short* Zsb  = (unsigned short*)(region + (size_t)N * 384);   // [N,64]
  // layer-2 layout aliases region (layer-1 dead by then)
  unsigned short* U0b  = (unsigned short*)region;                       // [N,40]
  unsigned short* U1b  = (unsigned short*)(region + (size_t)N * 80);    // [N,40]
  unsigned short* Us2b = (unsigned short*)(region + (size_t)N * 160);   // [N,64]
  unsigned short* Z2sb = (unsigned short*)(region + (size_t)N * 288);   // [N,64]
  // radix temporaries alias region (dead before gemm1)
  unsigned int* packed = (unsigned int*)region;                        // E*4
  unsigned char* pksrc = (unsigned char*)(region + (size_t)E * 4);     // E*1
  int* histGd = (int*)(region + (((size_t)E * 5 + 256 + 255) & ~(size_t)255));
  int* histGs = histGd + (size_t)MAXBUK * NBLK_PART;

  k_passA<<<NBLK_PART, 256, 0, stream>>>(src, dst, E, cpb, histGd, histGs, nbuk);
  k_scanA<<<2 * nbuk, 256, 0, stream>>>(histGd, histGs, buktotD, buktotS, nbuk);
  k_scanB<<<2, 256, 0, stream>>>(buktotD, buktotS, nbuk);
  k_passB<<<NBLK_PART, 256, 0, stream>>>(src, dst, E, cpb, histGd, histGs, buktotD, buktotS,
                                         nbuk, packed, pksrc);
  k_passC<<<nbuk, 256, 0, stream>>>(packed, buktotD, nbuk, E, N, csr_src, row_ptr);
  k_passC2<<<nbuk, 256, 0, stream>>>(pksrc, buktotS, nbuk, E, N, dinv);

  k_wfrag<<<(4 * 12 * 64 + 255) / 256, 256, 0, stream>>>(W1, Wfrag1, 128, 64, 12);
  k_wfrag<<<(2 * 8 * 64 + 255) / 256, 256, 0, stream>>>(W2, Wfrag2, 64, 40, 8);

  const int pb2 = ((size_t)N * 32 + 255) / 256;  // 2 nodes per wave
  const int gb = (N + 63) / 64;

  // layer 1: [Y0b|Y1b|Ys2b] = bf16(x) @ Weff1 (Ys2 cols dinv-scaled)
  k_gemm_mfma<128, 12, false, 128, 64, 128, 192, 64, 64, 64>
      <<<gb, 256, 0, stream>>>(x, Wfrag1, dinv, Y0b, Y1b, Ys2b, N);
  // Zs = dinv*(Y1 - dinv*G(Ys2))  -> bf16
  k_prop9<64, 64, 64, false, false, true, true><<<pb2, 256, 0, stream>>>(
      Ys2b, Y1b, nullptr, dinv, csr_src, row_ptr, Zsb, N);
  // h = relu(Y0 - dinv*G(Zs) + b1) -> bf16
  k_prop9<64, 64, 64, true, true, false, true><<<pb2, 256, 0, stream>>>(
      Zsb, Y0b, b1, dinv, csr_src, row_ptr, hb, N);
  // layer 2: [U0b|U1b|Us2b] = h @ Weff2 (Us2 cols dinv-scaled)
  k_gemm_mfma<64, 8, true, 64, 40, 80, 120, 40, 40, 64>
      <<<gb, 256, 0, stream>>>(hb, Wfrag2, dinv, U0b, U1b, Us2b, N);
  // Z2s = dinv*(U1 - dinv*G(Us2)) -> bf16
  k_prop9<40, 40, 64, false, false, true, true><<<pb2, 256, 0, stream>>>(
      Us2b, U1b, nullptr, dinv, csr_src, row_ptr, Z2sb, N);
  // out = U0 - dinv*G(Z2s) + b2  (fp32)
  k_prop9<40, 40, 40, false, true, false, false><<<pb2, 256, 0, stream>>>(
      Z2sb, U0b, b2, dinv, csr_src, row_ptr, out, N);
}